// Round 3
// baseline (338.144 us; speedup 1.0000x reference)
//
#include <hip/hip_runtime.h>

typedef unsigned short u16;
typedef unsigned int u32;
typedef __attribute__((ext_vector_type(8))) short bf16x8;
typedef __attribute__((ext_vector_type(4))) float f32x4;

#define DEV static __device__ __forceinline__

constexpr int B_ = 2, S_ = 1024, DM_ = 2048, H_ = 16, HKV_ = 4, DH_ = 128, NB_ = 16, BLK_ = 64, GH_ = 128;
constexpr int M_ = B_ * S_;                 // 2048 token rows
constexpr float EPS_ = 1e-6f;
constexpr float SCALE_ = 0.08838834764831845f;   // 1/sqrt(128); also gate scale (GH=128)

DEV u16 f2bf(float f) {
    u32 u = __float_as_uint(f);
    u += 0x7fffu + ((u >> 16) & 1u);
    return (u16)(u >> 16);
}
DEV float bf2f(u16 h) { return __uint_as_float(((u32)h) << 16); }

// async global->LDS, 16B per lane. LDS dest is wave-uniform base (+lane*16 implicit).
DEV void gload16(const void* g, void* l) {
    __builtin_amdgcn_global_load_lds((const __attribute__((address_space(1))) void*)g,
                                     (__attribute__((address_space(3))) void*)l, 16, 0, 0);
}

// ---------------- f32 -> bf16 convert (vectorized) ----------------
__global__ void cvt_kernel(const float* __restrict__ in, u16* __restrict__ out, int n) {
    int i = (blockIdx.x * blockDim.x + threadIdx.x) * 4;
    int stride = gridDim.x * blockDim.x * 4;
    for (; i < n; i += stride) {
        float4 v = *reinterpret_cast<const float4*>(in + i);
        uint2 o;
        o.x = (u32)f2bf(v.x) | ((u32)f2bf(v.y) << 16);
        o.y = (u32)f2bf(v.z) | ((u32)f2bf(v.w) << 16);
        *reinterpret_cast<uint2*>(out + i) = o;
    }
}

// ---------------- fused weight transpose+convert: wq/wk/wv -> wqkvT, wo -> woT ----------------
// all weights are f32 [2048][Cc]; output bf16 [Cc][2048] at the right row offset.
__global__ void wtrans_all_kernel(const float* __restrict__ wq, const float* __restrict__ wk,
                                  const float* __restrict__ wv, const float* __restrict__ wo,
                                  u16* __restrict__ wqkvT, u16* __restrict__ woT) {
    __shared__ float tile[32][33];
    int bx = blockIdx.x;
    const float* in; u16* out; int Cc, c0;
    if (bx < 64)      { in = wq; out = wqkvT;                 Cc = 2048; c0 = bx * 32; }
    else if (bx < 80) { in = wk; out = wqkvT + 2048UL * 2048; Cc = 512;  c0 = (bx - 64) * 32; }
    else if (bx < 96) { in = wv; out = wqkvT + 2560UL * 2048; Cc = 512;  c0 = (bx - 80) * 32; }
    else              { in = wo; out = woT;                   Cc = 2048; c0 = (bx - 96) * 32; }
    int r0 = blockIdx.y * 32;
    int tx = threadIdx.x & 31, ty = threadIdx.x >> 5;   // 256 threads
    for (int i = 0; i < 4; i++) {
        int r = ty + i * 8;
        tile[r][tx] = in[(long)(r0 + r) * Cc + c0 + tx];
    }
    __syncthreads();
    for (int i = 0; i < 4; i++) {
        int r = ty + i * 8;
        out[(long)(c0 + r) * 2048 + r0 + tx] = f2bf(tile[tx][r]);
    }
}

// ---------------- V transpose: qkv bf16 [b*S][3072] (v at col 2560) -> vt bf16 [b][kv][DH][S] ----------------
__global__ void vtrans_kernel(const u16* __restrict__ qkv, u16* __restrict__ vt) {
    __shared__ u16 tile[32][34];
    int z = blockIdx.z;                 // b*HKV + kv
    int b = z >> 2, kv = z & 3;
    int c0 = blockIdx.x * 32;           // feature 0..127
    int r0 = blockIdx.y * 32;           // s 0..1023
    int tx = threadIdx.x & 31, ty = threadIdx.x >> 5;
    const u16* ip = qkv + (long)b * S_ * 3072 + 2560 + kv * DH_;
    for (int i = 0; i < 4; i++) {
        int r = ty + i * 8;
        tile[r][tx] = ip[(long)(r0 + r) * 3072 + c0 + tx];
    }
    __syncthreads();
    u16* op = vt + (long)z * DH_ * S_;
    for (int i = 0; i < 4; i++) {
        int r = ty + i * 8;
        op[(long)(c0 + r) * S_ + r0 + tx] = tile[tx][r];
    }
}

// ---------------- bf16 MFMA GEMM: double-buffered LDS + both-sides XOR swizzle ----------------
// LDS tile logical [128 rows][64 k] bf16, row stride 128B. Swizzle: u16 col ^= (row&7)<<3.
// Staged via gload_lds with INVERSE-swizzled global source col (rule #21).
__global__ __launch_bounds__(256, 2) void gemm_bf16_kernel(
    const u16* __restrict__ A, const u16* __restrict__ Bt,
    float* __restrict__ Cf, u16* __restrict__ Cb, int Nn, int Kk) {
    __shared__ u16 As[2][128 * 64];
    __shared__ u16 Bs[2][128 * 64];
    int m0 = blockIdx.y * 128, n0 = blockIdx.x * 128;
    int t = threadIdx.x;
    int wave = t >> 6, lane = t & 63;
    int wm = wave >> 1, wn = wave & 1;
    int lr = lane & 15, lg = lane >> 4;
    // staging: chunk c = 1KB = 8 rows x 128B; lane covers row c*8+(lane>>3), seg (lane&7)*16B
    int srow = lane >> 3;
    int scol = (((lane & 7) * 8) ^ (srow << 3));        // u16 source col (inverse swizzle)
    int swz = (lr & 7) << 3;                            // u16 read swizzle
    f32x4 acc[4][4] = {};
#define GSTAGE(ktel, db)                                                       \
    {                                                                          \
        const u16* Ab = A + (long)m0 * Kk + (ktel);                            \
        const u16* Bb = Bt + (long)n0 * Kk + (ktel);                           \
        _Pragma("unroll")                                                      \
        for (int i = 0; i < 4; i++) {                                          \
            int c = wave * 4 + i;                                              \
            int row = c * 8 + srow;                                            \
            gload16(Ab + (long)row * Kk + scol, &As[db][c * 512]);             \
            gload16(Bb + (long)row * Kk + scol, &Bs[db][c * 512]);             \
        }                                                                      \
    }
    GSTAGE(0, 0);
    __syncthreads();
    int nk = Kk >> 6;
    for (int kt = 0; kt < nk; kt++) {
        int db = kt & 1;
        if (kt + 1 < nk) GSTAGE((kt + 1) << 6, db ^ 1);
#pragma unroll
        for (int kk = 0; kk < 64; kk += 32) {
            bf16x8 af[4], bfr[4];
            int kcol = (kk + lg * 8) ^ swz;
#pragma unroll
            for (int i = 0; i < 4; i++) {
                af[i]  = *reinterpret_cast<const bf16x8*>(&As[db][(wm * 64 + i * 16 + lr) * 64 + kcol]);
                bfr[i] = *reinterpret_cast<const bf16x8*>(&Bs[db][(wn * 64 + i * 16 + lr) * 64 + kcol]);
            }
#pragma unroll
            for (int mi = 0; mi < 4; mi++)
#pragma unroll
                for (int ni = 0; ni < 4; ni++)
                    acc[mi][ni] = __builtin_amdgcn_mfma_f32_16x16x32_bf16(af[mi], bfr[ni], acc[mi][ni], 0, 0, 0);
        }
        __syncthreads();
    }
#undef GSTAGE
    if (Cb) {
#pragma unroll
        for (int mi = 0; mi < 4; mi++)
#pragma unroll
            for (int ni = 0; ni < 4; ni++)
#pragma unroll
                for (int j = 0; j < 4; j++) {
                    int r = m0 + wm * 64 + mi * 16 + lg * 4 + j;
                    int c = n0 + wn * 64 + ni * 16 + lr;
                    Cb[(long)r * Nn + c] = f2bf(acc[mi][ni][j]);
                }
    } else {
#pragma unroll
        for (int mi = 0; mi < 4; mi++)
#pragma unroll
            for (int ni = 0; ni < 4; ni++)
#pragma unroll
                for (int j = 0; j < 4; j++) {
                    int r = m0 + wm * 64 + mi * 16 + lg * 4 + j;
                    int c = n0 + wn * 64 + ni * 16 + lr;
                    Cf[(long)r * Nn + c] = acc[mi][ni][j];
                }
    }
}

// ---------------- RMS norm + RoPE + qg/qgp (reads bf16 qkv: q cols 0..2047, k cols 2048..2559) ----------------
__global__ void normrope_kernel(
    const u16* __restrict__ qkv,
    const float* __restrict__ qw, const float* __restrict__ kw,
    const float* __restrict__ cosp, const float* __restrict__ sinp,
    const float* __restrict__ cosgq, const float* __restrict__ singq,
    const float* __restrict__ gate_wq,
    u16* __restrict__ qr, u16* __restrict__ kr, u16* __restrict__ kn,
    float* __restrict__ qgp) {
    int bs = blockIdx.x;
    int s = bs & (S_ - 1);
    int t = threadIdx.x;
    int w = t >> 6, lane = t & 63;
    __shared__ float qgl[HKV_][DH_];
    float c0 = cosp[s * DH_ + lane], c1 = cosp[s * DH_ + lane + 64];
    float s0 = sinp[s * DH_ + lane], s1 = sinp[s * DH_ + lane + 64];
    float qg0 = 0.f, qg1 = 0.f;
    const u16* qrow = qkv + (long)bs * 3072;
    for (int g = 0; g < 4; g++) {
        int h = w * 4 + g;
        float x0 = bf2f(qrow[h * DH_ + lane]), x1 = bf2f(qrow[h * DH_ + lane + 64]);
        float ss = x0 * x0 + x1 * x1;
        for (int m = 1; m < 64; m <<= 1) ss += __shfl_xor(ss, m);
        float r = rsqrtf(ss * (1.0f / DH_) + EPS_);
        float n0 = x0 * r * qw[lane], n1 = x1 * r * qw[lane + 64];
        qg0 += n0; qg1 += n1;
        u16* qrp = qr + (long)bs * (H_ * DH_) + h * DH_;
        qrp[lane]      = f2bf(n0 * c0 - n1 * s0);
        qrp[lane + 64] = f2bf(n1 * c1 + n0 * s1);
    }
    {
        const u16* krow = qkv + (long)bs * 3072 + 2048 + w * DH_;
        float x0 = bf2f(krow[lane]), x1 = bf2f(krow[lane + 64]);
        float ss = x0 * x0 + x1 * x1;
        for (int m = 1; m < 64; m <<= 1) ss += __shfl_xor(ss, m);
        float r = rsqrtf(ss * (1.0f / DH_) + EPS_);
        float n0 = x0 * r * kw[lane], n1 = x1 * r * kw[lane + 64];
        u16* knp = kn + (long)bs * (HKV_ * DH_) + w * DH_;
        knp[lane] = f2bf(n0); knp[lane + 64] = f2bf(n1);
        u16* krp = kr + (long)bs * (HKV_ * DH_) + w * DH_;
        krp[lane]      = f2bf(n0 * c0 - n1 * s0);
        krp[lane + 64] = f2bf(n1 * c1 + n0 * s1);
    }
    if (s >= S_ / 2) {    // qg/qgp only needed for the loss rows
        qg0 *= 0.25f; qg1 *= 0.25f;
        float cg0 = cosgq[s * DH_ + lane], cg1 = cosgq[s * DH_ + lane + 64];
        float sg0 = singq[s * DH_ + lane], sg1 = singq[s * DH_ + lane + 64];
        qgl[w][lane]      = qg0 * cg0 - qg1 * sg0;
        qgl[w][lane + 64] = qg1 * cg1 + qg0 * sg1;
        __syncthreads();
        for (int rep = 0; rep < 2; rep++) {
            int kv = (t >> 7) + rep * 2;
            int e = t & 127;
            float acc = 0.f;
            const float* qv = qgl[kv];
            for (int d = 0; d < DH_; d++) acc += qv[d] * gate_wq[d * GH_ + e];
            qgp[((long)bs * HKV_ + kv) * GH_ + e] = acc;
        }
    }
}

// ---------------- kp / kgp (+ zero the loss slot) ----------------
__global__ void kp_kernel(const u16* __restrict__ kn, const float* __restrict__ cosb,
                          const float* __restrict__ sinb, const float* __restrict__ gate_wk,
                          float* __restrict__ kgp, float* __restrict__ loss_slot) {
    int z = blockIdx.x;                 // (b*NB + n)*HKV + kv
    int kv = z & 3, n = (z >> 2) & 15, b = z >> 6;
    int d = threadIdx.x;                // 128 threads
    __shared__ float kp[DH_], kpr[DH_];
    float acc = 0.f;
    const u16* base = kn + (((long)b * S_ + n * BLK_) * HKV_ + kv) * DH_ + d;
    for (int i = 0; i < BLK_; i++) acc += bf2f(base[(long)i * HKV_ * DH_]);
    kp[d] = acc * (1.0f / BLK_);
    __syncthreads();
    float rot = (d < 64) ? -kp[d + 64] : kp[d - 64];
    kpr[d] = kp[d] * cosb[n * DH_ + d] + rot * sinb[n * DH_ + d];
    __syncthreads();
    float a2 = 0.f;
    for (int dd = 0; dd < DH_; dd++) a2 += kpr[dd] * gate_wk[dd * GH_ + d];
    kgp[(long)z * GH_ + d] = a2;
    if (z == 0 && d == 0) *loss_slot = 0.0f;
}

// ---------------- flash attention: K dbuf-LDS (swizzled), V direct-from-global (L2-resident) ----------------
__global__ __launch_bounds__(256, 3) void attn_kernel(
    const u16* __restrict__ qr, const u16* __restrict__ kr, const u16* __restrict__ vt,
    u16* __restrict__ attn_out, float* __restrict__ gtraw,
    float* __restrict__ mfin, float* __restrict__ lfin) {
    __shared__ u16 Ks[2][BLK_ * DH_];
    __shared__ u16 Ps[4][16][72];
    int blk = blockIdx.x;
    int qt = blk & 15, h = (blk >> 4) & 15, b = blk >> 8;
    int kv = h >> 2;
    int t = threadIdx.x, wave = t >> 6, lane = t & 63;
    int lr = lane & 15, lg = lane >> 4;
    int q0 = qt * 64;
    const u16* kbase = kr + (((long)b * S_) * HKV_ + kv) * DH_;       // row stride 512
    const u16* vbase = vt + ((long)(b * HKV_ + kv)) * DH_ * S_;       // row stride 1024
    bf16x8 qfr[4];
    {
        long qbase = (((long)b * S_ + q0 + wave * 16 + lr) * H_ + h) * DH_;
#pragma unroll
        for (int ko = 0; ko < 4; ko++)
            qfr[ko] = *reinterpret_cast<const bf16x8*>(qr + qbase + ko * 32 + lg * 8);
    }
    f32x4 acco[8] = {};
    float mrun[4], lrun[4];
#pragma unroll
    for (int j = 0; j < 4; j++) { mrun[j] = -INFINITY; lrun[j] = 0.f; }

    int krow = (lane >> 4), kseg = (lane & 15) * 16;   // K chunk: 4 rows x 256B

#define STAGEK(nt, db)                                                                    \
    {                                                                                     \
        const u16* kb = kbase + (long)(nt) * 64 * 512;                                    \
        u16* uK = &Ks[db][0];                                                             \
        _Pragma("unroll")                                                                 \
        for (int i = 0; i < 4; i++) {                                                     \
            int c = wave * 4 + i;                                                         \
            int r = c * 4 + krow;                                                         \
            int col = (kseg ^ ((r & 7) << 4)) >> 1;                                       \
            gload16(kb + (long)r * 512 + col, uK + c * 512);                              \
        }                                                                                 \
    }

    STAGEK(0, 0);
    __syncthreads();

    for (int n = 0; n <= qt; n++) {
        int d = n & 1;
        // V fragments direct from global (issue early; L2-resident, reused by 64 blocks)
        bf16x8 vfr[2][8];
        const u16* vb = vbase + n * 64;
#pragma unroll
        for (int ko = 0; ko < 2; ko++)
#pragma unroll
            for (int nf = 0; nf < 8; nf++)
                vfr[ko][nf] = *reinterpret_cast<const bf16x8*>(vb + (long)(nf * 16 + lr) * S_ + ko * 32 + lg * 8);
        if (n < qt) STAGEK(n + 1, d ^ 1);     // prefetch next K tile
        const u16* uK = &Ks[d][0];
        int sw = (lr & 7) << 3;
        f32x4 sacc[4] = {};
#pragma unroll
        for (int ni = 0; ni < 4; ni++) {
            int rr = ni * 16 + lr;
#pragma unroll
            for (int ko = 0; ko < 4; ko++) {
                bf16x8 kfr = *reinterpret_cast<const bf16x8*>(uK + rr * 128 + ((ko * 32 + lg * 8) ^ sw));
                sacc[ni] = __builtin_amdgcn_mfma_f32_16x16x32_bf16(qfr[ko], kfr, sacc[ni], 0, 0, 0);
            }
        }
        float bm[4] = {-INFINITY, -INFINITY, -INFINITY, -INFINITY};
        float sval[4][4];
#pragma unroll
        for (int ni = 0; ni < 4; ni++) {
            int key = n * 64 + ni * 16 + lr;
#pragma unroll
            for (int j = 0; j < 4; j++) {
                int qrow = q0 + wave * 16 + lg * 4 + j;
                float v = sacc[ni][j] * SCALE_;
                if (key > qrow) v = -INFINITY;
                sval[ni][j] = v;
                bm[j] = fmaxf(bm[j], v);
            }
        }
#pragma unroll
        for (int j = 0; j < 4; j++)
            for (int m = 1; m < 16; m <<= 1)
                bm[j] = fmaxf(bm[j], __shfl_xor(bm[j], m));
        if (lr == 0) {
#pragma unroll
            for (int j = 0; j < 4; j++) {
                int qrow = q0 + wave * 16 + lg * 4 + j;
                gtraw[(((long)b * H_ + h) * S_ + qrow) * NB_ + n] = bm[j];
            }
        }
        float cfac[4], rs[4];
#pragma unroll
        for (int j = 0; j < 4; j++) {
            float mnew = fmaxf(mrun[j], bm[j]);
            cfac[j] = __expf(mrun[j] - mnew);
            mrun[j] = mnew;
            rs[j] = 0.f;
        }
#pragma unroll
        for (int ni = 0; ni < 4; ni++)
#pragma unroll
            for (int j = 0; j < 4; j++) {
                float p = __expf(sval[ni][j] - mrun[j]);
                rs[j] += p;
                Ps[wave][lg * 4 + j][ni * 16 + lr] = f2bf(p);
            }
#pragma unroll
        for (int j = 0; j < 4; j++) {
            float t2 = rs[j];
            for (int m = 1; m < 16; m <<= 1) t2 += __shfl_xor(t2, m);
            lrun[j] = lrun[j] * cfac[j] + t2;
        }
#pragma unroll
        for (int nf = 0; nf < 8; nf++)
#pragma unroll
            for (int j = 0; j < 4; j++) acco[nf][j] *= cfac[j];
#pragma unroll
        for (int ko = 0; ko < 2; ko++) {
            bf16x8 pf = *reinterpret_cast<const bf16x8*>(&Ps[wave][lr][ko * 32 + lg * 8]);
#pragma unroll
            for (int nf = 0; nf < 8; nf++)
                acco[nf] = __builtin_amdgcn_mfma_f32_16x16x32_bf16(pf, vfr[ko][nf], acco[nf], 0, 0, 0);
        }
        __syncthreads();   // K dbuf handoff (drains staged loads)
    }
#undef STAGEK
    float invl[4];
#pragma unroll
    for (int j = 0; j < 4; j++) invl[j] = 1.0f / lrun[j];
#pragma unroll
    for (int nf = 0; nf < 8; nf++)
#pragma unroll
        for (int j = 0; j < 4; j++) {
            int qrow = q0 + wave * 16 + lg * 4 + j;
            attn_out[((long)b * S_ + qrow) * (H_ * DH_) + h * DH_ + nf * 16 + lr] = f2bf(acco[nf][j] * invl[j]);
        }
    if (lr == 0) {
#pragma unroll
        for (int j = 0; j < 4; j++) {
            int qrow = q0 + wave * 16 + lg * 4 + j;
            mfin[((long)b * H_ + h) * S_ + qrow] = mrun[j];
            lfin[((long)b * H_ + h) * S_ + qrow] = lrun[j];
        }
    }
}

// ---------------- gate loss: 4 waves/block, one (b,s) per wave ----------------
__global__ void loss_kernel(const float* __restrict__ gtraw, const float* __restrict__ mfin,
                            const float* __restrict__ lfin, const float* __restrict__ qgp,
                            const float* __restrict__ kgp, float* __restrict__ out_loss) {
    int wid = threadIdx.x >> 6, lane = threadIdx.x & 63;
    int blk = blockIdx.x * 4 + wid;     // b*(S/2) + (s-512)
    int b = blk >> 9, s = 512 + (blk & 511);
    int kv = lane >> 4, n = lane & 15;
    int nvis = (s >> 6) + 1;
    float tn = 0.f;
    if (n < nvis) {
        for (int g = 0; g < 4; g++) {
            int h = kv * 4 + g;
            long idx = ((long)b * H_ + h) * S_ + s;
            float gt = __expf(gtraw[idx * NB_ + n] - mfin[idx]) / lfin[idx];
            tn = fmaxf(tn, gt);
        }
    }
    float tsum = tn;
    for (int m = 1; m < 16; m <<= 1) tsum += __shfl_xor(tsum, m);
    tn = tn / (tsum + 1e-9f);
    float z = -INFINITY;
    if (n < nvis) {
        const float* qv = qgp + (((long)b * S_ + s) * HKV_ + kv) * GH_;
        const float* kvp = kgp + (((long)b * NB_ + n) * HKV_ + kv) * GH_;
        float acc = 0.f;
        for (int d = 0; d < GH_; d++) acc += qv[d] * kvp[d];
        z = acc * SCALE_;
    }
    float zmax = z;
    for (int m = 1; m < 16; m <<= 1) zmax = fmaxf(zmax, __shfl_xor(zmax, m));
    float ez = (n < nvis) ? __expf(z - zmax) : 0.f;
    float se = ez;
    for (int m = 1; m < 16; m <<= 1) se += __shfl_xor(se, m);
    float logZ = zmax + __logf(se);
    float kl = 0.f;
    if (tn > 0.f) kl = tn * (__logf(tn) - (z - logZ));
    for (int m = 1; m < 16; m <<= 1) kl += __shfl_xor(kl, m);
    kl += __shfl_xor(kl, 16);
    kl += __shfl_xor(kl, 32);
    __shared__ float part[4];
    if (lane == 0) part[wid] = kl;
    __syncthreads();
    if (threadIdx.x == 0)
        atomicAdd(out_loss, (part[0] + part[1] + part[2] + part[3]) * (1.0f / 65536.0f));
}

extern "C" void kernel_launch(void* const* d_in, const int* in_sizes, int n_in,
                              void* d_out, int out_size, void* d_ws, size_t ws_size,
                              hipStream_t stream) {
    const float* hs    = (const float*)d_in[0];
    const float* wq    = (const float*)d_in[1];
    const float* wk    = (const float*)d_in[2];
    const float* wv    = (const float*)d_in[3];
    const float* wo    = (const float*)d_in[4];
    const float* qnw   = (const float*)d_in[5];
    const float* knw   = (const float*)d_in[6];
    const float* gwq   = (const float*)d_in[7];
    const float* gwk   = (const float*)d_in[8];
    const float* cosp  = (const float*)d_in[9];
    const float* sinp  = (const float*)d_in[10];
    const float* cosgq = (const float*)d_in[11];
    const float* singq = (const float*)d_in[12];
    const float* cosb  = (const float*)d_in[13];
    const float* sinb  = (const float*)d_in[14];
    // d_in[15] (block_attention_mask) is deterministic: n*64 <= s — never read.

    char* ws = (char*)d_ws;
    size_t off = 0;
    auto alloc = [&](size_t bytes) { void* p = ws + off; off += (bytes + 255) & ~255ULL; return p; };
    u16*  hsb    = (u16*)alloc((size_t)M_ * DM_ * 2);       // 8MB; dead after QKV gemm -> reused as attnb
    u16*  wqkvT  = (u16*)alloc(3072UL * 2048 * 2);          // 12MB combined [wqT; wkT; wvT]
    u16*  woT    = (u16*)alloc(2048UL * 2048 * 2);          // 8MB
    u16*  qkvb   = (u16*)alloc((size_t)M_ * 3072 * 2);      // 12MB bf16 QKV output
    u16*  qrb    = (u16*)alloc(2048UL * 2048 * 2);
    u16*  krb    = (u16*)alloc(2048UL * 512 * 2);
    u16*  knb    = (u16*)alloc(2048UL * 512 * 2);
    u16*  vtb    = (u16*)alloc(8UL * 128 * 1024 * 2);
    float* qgp   = (float*)alloc(2048UL * 4 * 128 * 4);
    float* kgp   = (float*)alloc(2UL * 16 * 4 * 128 * 4);
    float* gtraw = (float*)alloc(2UL * 16 * 1024 * 16 * 4);
    float* mfin  = (float*)alloc(2UL * 16 * 1024 * 4);
    float* lfin  = (float*)alloc(2UL * 16 * 1024 * 4);
    u16*  attnb  = hsb;                                     // alias: hsb dead before attn writes

    float* out = (float*)d_out;
    float* loss_slot = out + (size_t)M_ * DM_;

    cvt_kernel<<<1024, 256, 0, stream>>>(hs, hsb, M_ * DM_);
    wtrans_all_kernel<<<dim3(160, 64), 256, 0, stream>>>(wq, wk, wv, wo, wqkvT, woT);

    // fused QKV projection: [2048][2048] @ [2048][3072] -> bf16 [2048][3072]
    gemm_bf16_kernel<<<dim3(24, 16), 256, 0, stream>>>(hsb, wqkvT, nullptr, qkvb, 3072, 2048);

    normrope_kernel<<<2048, 256, 0, stream>>>(qkvb, qnw, knw, cosp, sinp, cosgq, singq, gwq,
                                              qrb, krb, knb, qgp);
    vtrans_kernel<<<dim3(4, 32, 8), 256, 0, stream>>>(qkvb, vtb);
    kp_kernel<<<128, 128, 0, stream>>>(knb, cosb, sinb, gwk, kgp, loss_slot);

    attn_kernel<<<512, 256, 0, stream>>>(qrb, krb, vtb, attnb, gtraw, mfin, lfin);
    loss_kernel<<<256, 256, 0, stream>>>(gtraw, mfin, lfin, qgp, kgp, loss_slot);

    // output projection: [2048][2048]bf16 @ [2048][2048] -> f32 out
    gemm_bf16_kernel<<<dim3(16, 16), 256, 0, stream>>>(attnb, woT, out, nullptr, 2048, 2048);
}

// Round 4
// 265.396 us; speedup vs baseline: 1.2741x; 1.2741x over previous
//
#include <hip/hip_runtime.h>

typedef unsigned short u16;
typedef unsigned int u32;
typedef __attribute__((ext_vector_type(8))) short bf16x8;
typedef __attribute__((ext_vector_type(4))) float f32x4;

#define DEV static __device__ __forceinline__

constexpr int B_ = 2, S_ = 1024, DM_ = 2048, H_ = 16, HKV_ = 4, DH_ = 128, NB_ = 16, BLK_ = 64, GH_ = 128;
constexpr int M_ = B_ * S_;                 // 2048 token rows
constexpr float EPS_ = 1e-6f;
constexpr float SCALE_ = 0.08838834764831845f;   // 1/sqrt(128); also gate scale (GH=128)

DEV u16 f2bf(float f) {
    u32 u = __float_as_uint(f);
    u += 0x7fffu + ((u >> 16) & 1u);
    return (u16)(u >> 16);
}
DEV float bf2f(u16 h) { return __uint_as_float(((u32)h) << 16); }

// async global->LDS, 16B per lane. LDS dest is wave-uniform base (+lane*16 implicit).
DEV void gload16(const void* g, void* l) {
    __builtin_amdgcn_global_load_lds((const __attribute__((address_space(1))) void*)g,
                                     (__attribute__((address_space(3))) void*)l, 16, 0, 0);
}

// ---------------- f32 -> bf16 convert (vectorized) ----------------
__global__ void cvt_kernel(const float* __restrict__ in, u16* __restrict__ out, int n) {
    int i = (blockIdx.x * blockDim.x + threadIdx.x) * 4;
    int stride = gridDim.x * blockDim.x * 4;
    for (; i < n; i += stride) {
        float4 v = *reinterpret_cast<const float4*>(in + i);
        uint2 o;
        o.x = (u32)f2bf(v.x) | ((u32)f2bf(v.y) << 16);
        o.y = (u32)f2bf(v.z) | ((u32)f2bf(v.w) << 16);
        *reinterpret_cast<uint2*>(out + i) = o;
    }
}

// ---------------- fused weight transpose+convert: wq/wk/wv -> wqkvT, wo -> woT ----------------
__global__ void wtrans_all_kernel(const float* __restrict__ wq, const float* __restrict__ wk,
                                  const float* __restrict__ wv, const float* __restrict__ wo,
                                  u16* __restrict__ wqkvT, u16* __restrict__ woT) {
    __shared__ float tile[32][33];
    int bx = blockIdx.x;
    const float* in; u16* out; int Cc, c0;
    if (bx < 64)      { in = wq; out = wqkvT;                 Cc = 2048; c0 = bx * 32; }
    else if (bx < 80) { in = wk; out = wqkvT + 2048UL * 2048; Cc = 512;  c0 = (bx - 64) * 32; }
    else if (bx < 96) { in = wv; out = wqkvT + 2560UL * 2048; Cc = 512;  c0 = (bx - 80) * 32; }
    else              { in = wo; out = woT;                   Cc = 2048; c0 = (bx - 96) * 32; }
    int r0 = blockIdx.y * 32;
    int tx = threadIdx.x & 31, ty = threadIdx.x >> 5;   // 256 threads
    for (int i = 0; i < 4; i++) {
        int r = ty + i * 8;
        tile[r][tx] = in[(long)(r0 + r) * Cc + c0 + tx];
    }
    __syncthreads();
    for (int i = 0; i < 4; i++) {
        int r = ty + i * 8;
        out[(long)(c0 + r) * 2048 + r0 + tx] = f2bf(tile[tx][r]);
    }
}

// ---------------- V transpose: qkv bf16 [b*S][3072] (v at col 2560) -> vt bf16 [b][kv][DH][S] ----------------
__global__ void vtrans_kernel(const u16* __restrict__ qkv, u16* __restrict__ vt) {
    __shared__ u16 tile[32][34];
    int z = blockIdx.z;                 // b*HKV + kv
    int b = z >> 2, kv = z & 3;
    int c0 = blockIdx.x * 32;           // feature 0..127
    int r0 = blockIdx.y * 32;           // s 0..1023
    int tx = threadIdx.x & 31, ty = threadIdx.x >> 5;
    const u16* ip = qkv + (long)b * S_ * 3072 + 2560 + kv * DH_;
    for (int i = 0; i < 4; i++) {
        int r = ty + i * 8;
        tile[r][tx] = ip[(long)(r0 + r) * 3072 + c0 + tx];
    }
    __syncthreads();
    u16* op = vt + (long)z * DH_ * S_;
    for (int i = 0; i < 4; i++) {
        int r = ty + i * 8;
        op[(long)(c0 + r) * S_ + r0 + tx] = tile[tx][r];
    }
}

// ---------------- bf16 MFMA GEMM: double-buffered LDS + both-sides XOR swizzle ----------------
// LDS tile logical [128 rows][64 k] bf16, row stride 128B. Swizzle: u16 col ^= (row&7)<<3.
// Staged via gload_lds with INVERSE-swizzled global source col (rule #21).
__global__ __launch_bounds__(256, 2) void gemm_bf16_kernel(
    const u16* __restrict__ A, const u16* __restrict__ Bt,
    float* __restrict__ Cf, u16* __restrict__ Cb, int Nn, int Kk) {
    __shared__ u16 As[2][128 * 64];
    __shared__ u16 Bs[2][128 * 64];
    int m0 = blockIdx.y * 128, n0 = blockIdx.x * 128;
    int t = threadIdx.x;
    int wave = t >> 6, lane = t & 63;
    int wm = wave >> 1, wn = wave & 1;
    int lr = lane & 15, lg = lane >> 4;
    int srow = lane >> 3;
    int scol = (((lane & 7) * 8) ^ (srow << 3));        // u16 source col (inverse swizzle)
    int swz = (lr & 7) << 3;                            // u16 read swizzle
    f32x4 acc[4][4] = {};
#define GSTAGE(ktel, db)                                                       \
    {                                                                          \
        const u16* Ab = A + (long)m0 * Kk + (ktel);                            \
        const u16* Bb = Bt + (long)n0 * Kk + (ktel);                           \
        _Pragma("unroll")                                                      \
        for (int i = 0; i < 4; i++) {                                          \
            int c = wave * 4 + i;                                              \
            int row = c * 8 + srow;                                            \
            gload16(Ab + (long)row * Kk + scol, &As[db][c * 512]);             \
            gload16(Bb + (long)row * Kk + scol, &Bs[db][c * 512]);             \
        }                                                                      \
    }
    GSTAGE(0, 0);
    __syncthreads();
    int nk = Kk >> 6;
    for (int kt = 0; kt < nk; kt++) {
        int db = kt & 1;
        if (kt + 1 < nk) GSTAGE((kt + 1) << 6, db ^ 1);
#pragma unroll
        for (int kk = 0; kk < 64; kk += 32) {
            bf16x8 af[4], bfr[4];
            int kcol = (kk + lg * 8) ^ swz;
#pragma unroll
            for (int i = 0; i < 4; i++) {
                af[i]  = *reinterpret_cast<const bf16x8*>(&As[db][(wm * 64 + i * 16 + lr) * 64 + kcol]);
                bfr[i] = *reinterpret_cast<const bf16x8*>(&Bs[db][(wn * 64 + i * 16 + lr) * 64 + kcol]);
            }
            __builtin_amdgcn_s_setprio(1);
#pragma unroll
            for (int mi = 0; mi < 4; mi++)
#pragma unroll
                for (int ni = 0; ni < 4; ni++)
                    acc[mi][ni] = __builtin_amdgcn_mfma_f32_16x16x32_bf16(af[mi], bfr[ni], acc[mi][ni], 0, 0, 0);
            __builtin_amdgcn_s_setprio(0);
        }
        __syncthreads();
    }
#undef GSTAGE
    if (Cb) {
#pragma unroll
        for (int mi = 0; mi < 4; mi++)
#pragma unroll
            for (int ni = 0; ni < 4; ni++)
#pragma unroll
                for (int j = 0; j < 4; j++) {
                    int r = m0 + wm * 64 + mi * 16 + lg * 4 + j;
                    int c = n0 + wn * 64 + ni * 16 + lr;
                    Cb[(long)r * Nn + c] = f2bf(acc[mi][ni][j]);
                }
    } else {
#pragma unroll
        for (int mi = 0; mi < 4; mi++)
#pragma unroll
            for (int ni = 0; ni < 4; ni++)
#pragma unroll
                for (int j = 0; j < 4; j++) {
                    int r = m0 + wm * 64 + mi * 16 + lg * 4 + j;
                    int c = n0 + wn * 64 + ni * 16 + lr;
                    Cf[(long)r * Nn + c] = acc[mi][ni][j];
                }
    }
}

// ---------------- RMS norm + RoPE + qg/qgp (reads bf16 qkv: q cols 0..2047, k cols 2048..2559) ----------------
__global__ void normrope_kernel(
    const u16* __restrict__ qkv,
    const float* __restrict__ qw, const float* __restrict__ kw,
    const float* __restrict__ cosp, const float* __restrict__ sinp,
    const float* __restrict__ cosgq, const float* __restrict__ singq,
    const float* __restrict__ gate_wq,
    u16* __restrict__ qr, u16* __restrict__ kr, u16* __restrict__ kn,
    float* __restrict__ qgp) {
    int bs = blockIdx.x;
    int s = bs & (S_ - 1);
    int t = threadIdx.x;
    int w = t >> 6, lane = t & 63;
    __shared__ float qgl[HKV_][DH_];
    float c0 = cosp[s * DH_ + lane], c1 = cosp[s * DH_ + lane + 64];
    float s0 = sinp[s * DH_ + lane], s1 = sinp[s * DH_ + lane + 64];
    float qg0 = 0.f, qg1 = 0.f;
    const u16* qrow = qkv + (long)bs * 3072;
    for (int g = 0; g < 4; g++) {
        int h = w * 4 + g;
        float x0 = bf2f(qrow[h * DH_ + lane]), x1 = bf2f(qrow[h * DH_ + lane + 64]);
        float ss = x0 * x0 + x1 * x1;
        for (int m = 1; m < 64; m <<= 1) ss += __shfl_xor(ss, m);
        float r = rsqrtf(ss * (1.0f / DH_) + EPS_);
        float n0 = x0 * r * qw[lane], n1 = x1 * r * qw[lane + 64];
        qg0 += n0; qg1 += n1;
        u16* qrp = qr + (long)bs * (H_ * DH_) + h * DH_;
        qrp[lane]      = f2bf(n0 * c0 - n1 * s0);
        qrp[lane + 64] = f2bf(n1 * c1 + n0 * s1);
    }
    {
        const u16* krow = qkv + (long)bs * 3072 + 2048 + w * DH_;
        float x0 = bf2f(krow[lane]), x1 = bf2f(krow[lane + 64]);
        float ss = x0 * x0 + x1 * x1;
        for (int m = 1; m < 64; m <<= 1) ss += __shfl_xor(ss, m);
        float r = rsqrtf(ss * (1.0f / DH_) + EPS_);
        float n0 = x0 * r * kw[lane], n1 = x1 * r * kw[lane + 64];
        u16* knp = kn + (long)bs * (HKV_ * DH_) + w * DH_;
        knp[lane] = f2bf(n0); knp[lane + 64] = f2bf(n1);
        u16* krp = kr + (long)bs * (HKV_ * DH_) + w * DH_;
        krp[lane]      = f2bf(n0 * c0 - n1 * s0);
        krp[lane + 64] = f2bf(n1 * c1 + n0 * s1);
    }
    if (s >= S_ / 2) {    // qg/qgp only needed for the loss rows
        qg0 *= 0.25f; qg1 *= 0.25f;
        float cg0 = cosgq[s * DH_ + lane], cg1 = cosgq[s * DH_ + lane + 64];
        float sg0 = singq[s * DH_ + lane], sg1 = singq[s * DH_ + lane + 64];
        qgl[w][lane]      = qg0 * cg0 - qg1 * sg0;
        qgl[w][lane + 64] = qg1 * cg1 + qg0 * sg1;
        __syncthreads();
        for (int rep = 0; rep < 2; rep++) {
            int kv = (t >> 7) + rep * 2;
            int e = t & 127;
            float acc = 0.f;
            const float* qv = qgl[kv];
            for (int d = 0; d < DH_; d++) acc += qv[d] * gate_wq[d * GH_ + e];
            qgp[((long)bs * HKV_ + kv) * GH_ + e] = acc;
        }
    }
}

// ---------------- kp / kgp (+ zero the loss slot) ----------------
__global__ void kp_kernel(const u16* __restrict__ kn, const float* __restrict__ cosb,
                          const float* __restrict__ sinb, const float* __restrict__ gate_wk,
                          float* __restrict__ kgp, float* __restrict__ loss_slot) {
    int z = blockIdx.x;                 // (b*NB + n)*HKV + kv
    int kv = z & 3, n = (z >> 2) & 15, b = z >> 6;
    int d = threadIdx.x;                // 128 threads
    __shared__ float kp[DH_], kpr[DH_];
    float acc = 0.f;
    const u16* base = kn + (((long)b * S_ + n * BLK_) * HKV_ + kv) * DH_ + d;
    for (int i = 0; i < BLK_; i++) acc += bf2f(base[(long)i * HKV_ * DH_]);
    kp[d] = acc * (1.0f / BLK_);
    __syncthreads();
    float rot = (d < 64) ? -kp[d + 64] : kp[d - 64];
    kpr[d] = kp[d] * cosb[n * DH_ + d] + rot * sinb[n * DH_ + d];
    __syncthreads();
    float a2 = 0.f;
    for (int dd = 0; dd < DH_; dd++) a2 += kpr[dd] * gate_wk[dd * GH_ + d];
    kgp[(long)z * GH_ + d] = a2;
    if (z == 0 && d == 0) *loss_slot = 0.0f;
}

// ---------------- flash attention + gt raw stats (round-2 structure: K+V dbuf LDS, swizzled; + setprio) ----------------
// K logical (r in [0,64), k in [0,128)) stored at LDS byte r*256 + ((k*2) ^ ((r&7)<<4))
// V logical (r in [0,128), c in [0,64)) stored at LDS byte r*128 + ((c*2) ^ ((r&7)<<4))
__global__ __launch_bounds__(256, 2) void attn_kernel(
    const u16* __restrict__ qr, const u16* __restrict__ kr, const u16* __restrict__ vt,
    u16* __restrict__ attn_out, float* __restrict__ gtraw,
    float* __restrict__ mfin, float* __restrict__ lfin) {
    __shared__ u16 Ks[2][BLK_ * DH_];
    __shared__ u16 Vts[2][DH_ * BLK_];
    __shared__ u16 Ps[4][16][72];
    int blk = blockIdx.x;
    int qt = blk & 15, h = (blk >> 4) & 15, b = blk >> 8;
    int kv = h >> 2;
    int t = threadIdx.x, wave = t >> 6, lane = t & 63;
    int lr = lane & 15, lg = lane >> 4;
    int q0 = qt * 64;
    const u16* kbase = kr + (((long)b * S_) * HKV_ + kv) * DH_;       // row stride 512
    const u16* vbase = vt + ((long)(b * HKV_ + kv)) * DH_ * S_;       // row stride 1024
    bf16x8 qfr[4];
    {
        long qbase = (((long)b * S_ + q0 + wave * 16 + lr) * H_ + h) * DH_;
#pragma unroll
        for (int ko = 0; ko < 4; ko++)
            qfr[ko] = *reinterpret_cast<const bf16x8*>(qr + qbase + ko * 32 + lg * 8);
    }
    f32x4 acco[8] = {};
    float mrun[4], lrun[4];
#pragma unroll
    for (int j = 0; j < 4; j++) { mrun[j] = -INFINITY; lrun[j] = 0.f; }

    int krow = (lane >> 4), kseg = (lane & 15) * 16;   // K chunk: 4 rows x 256B
    int vrow = (lane >> 3), vseg = (lane & 7) * 16;    // V chunk: 8 rows x 128B

#define STAGE(nt, dbuf)                                                                   \
    {                                                                                     \
        const u16* kb = kbase + (long)(nt) * 64 * 512;                                    \
        const u16* vb = vbase + (nt) * 64;                                                \
        u16* uK = &Ks[dbuf][0];                                                           \
        u16* uV = &Vts[dbuf][0];                                                          \
        _Pragma("unroll")                                                                 \
        for (int i = 0; i < 4; i++) {                                                     \
            int c = wave * 4 + i;                                                         \
            {                                                                             \
                int r = c * 4 + krow;                                                     \
                int col = (kseg ^ ((r & 7) << 4)) >> 1;                                   \
                gload16(kb + (long)r * 512 + col, uK + c * 512);                          \
            }                                                                             \
            {                                                                             \
                int r = c * 8 + vrow;                                                     \
                int col = (vseg ^ ((r & 7) << 4)) >> 1;                                   \
                gload16(vb + (long)r * 1024 + col, uV + c * 512);                         \
            }                                                                             \
        }                                                                                 \
    }

    STAGE(0, 0);
    __syncthreads();   // drains vmcnt: tile 0 staged

    for (int n = 0; n <= qt; n++) {
        int d = n & 1;
        if (n < qt) STAGE(n + 1, d ^ 1);     // prefetch overlaps this iteration's compute
        const u16* uK = &Ks[d][0];
        const u16* uV = &Vts[d][0];
        int sw = (lr & 7) << 3;
        f32x4 sacc[4] = {};
        __builtin_amdgcn_s_setprio(1);
#pragma unroll
        for (int ni = 0; ni < 4; ni++) {
            int rr = ni * 16 + lr;
#pragma unroll
            for (int ko = 0; ko < 4; ko++) {
                bf16x8 kfr = *reinterpret_cast<const bf16x8*>(uK + rr * 128 + ((ko * 32 + lg * 8) ^ sw));
                sacc[ni] = __builtin_amdgcn_mfma_f32_16x16x32_bf16(qfr[ko], kfr, sacc[ni], 0, 0, 0);
            }
        }
        __builtin_amdgcn_s_setprio(0);
        float bm[4] = {-INFINITY, -INFINITY, -INFINITY, -INFINITY};
        float sval[4][4];
#pragma unroll
        for (int ni = 0; ni < 4; ni++) {
            int key = n * 64 + ni * 16 + lr;
#pragma unroll
            for (int j = 0; j < 4; j++) {
                int qrow = q0 + wave * 16 + lg * 4 + j;
                float v = sacc[ni][j] * SCALE_;
                if (key > qrow) v = -INFINITY;
                sval[ni][j] = v;
                bm[j] = fmaxf(bm[j], v);
            }
        }
#pragma unroll
        for (int j = 0; j < 4; j++)
            for (int m = 1; m < 16; m <<= 1)
                bm[j] = fmaxf(bm[j], __shfl_xor(bm[j], m));
        if (lr == 0) {
#pragma unroll
            for (int j = 0; j < 4; j++) {
                int qrow = q0 + wave * 16 + lg * 4 + j;
                gtraw[(((long)b * H_ + h) * S_ + qrow) * NB_ + n] = bm[j];
            }
        }
        float cfac[4], rs[4];
#pragma unroll
        for (int j = 0; j < 4; j++) {
            float mnew = fmaxf(mrun[j], bm[j]);
            cfac[j] = __expf(mrun[j] - mnew);
            mrun[j] = mnew;
            rs[j] = 0.f;
        }
#pragma unroll
        for (int ni = 0; ni < 4; ni++)
#pragma unroll
            for (int j = 0; j < 4; j++) {
                float p = __expf(sval[ni][j] - mrun[j]);
                rs[j] += p;
                Ps[wave][lg * 4 + j][ni * 16 + lr] = f2bf(p);
            }
#pragma unroll
        for (int j = 0; j < 4; j++) {
            float t2 = rs[j];
            for (int m = 1; m < 16; m <<= 1) t2 += __shfl_xor(t2, m);
            lrun[j] = lrun[j] * cfac[j] + t2;
        }
#pragma unroll
        for (int nf = 0; nf < 8; nf++)
#pragma unroll
            for (int j = 0; j < 4; j++) acco[nf][j] *= cfac[j];
        __builtin_amdgcn_s_setprio(1);
#pragma unroll
        for (int ko = 0; ko < 2; ko++) {
            bf16x8 pf = *reinterpret_cast<const bf16x8*>(&Ps[wave][lr][ko * 32 + lg * 8]);
#pragma unroll
            for (int nf = 0; nf < 8; nf++) {
                int rr = nf * 16 + lr;
                bf16x8 vf = *reinterpret_cast<const bf16x8*>(uV + rr * 64 + ((ko * 32 + lg * 8) ^ sw));
                acco[nf] = __builtin_amdgcn_mfma_f32_16x16x32_bf16(pf, vf, acco[nf], 0, 0, 0);
            }
        }
        __builtin_amdgcn_s_setprio(0);
        __syncthreads();   // one barrier/iter: staged d^1 ready, reads of d done
    }
    float invl[4];
#pragma unroll
    for (int j = 0; j < 4; j++) invl[j] = 1.0f / lrun[j];
#pragma unroll
    for (int nf = 0; nf < 8; nf++)
#pragma unroll
        for (int j = 0; j < 4; j++) {
            int qrow = q0 + wave * 16 + lg * 4 + j;
            attn_out[((long)b * S_ + qrow) * (H_ * DH_) + h * DH_ + nf * 16 + lr] = f2bf(acco[nf][j] * invl[j]);
        }
    if (lr == 0) {
#pragma unroll
        for (int j = 0; j < 4; j++) {
            int qrow = q0 + wave * 16 + lg * 4 + j;
            mfin[((long)b * H_ + h) * S_ + qrow] = mrun[j];
            lfin[((long)b * H_ + h) * S_ + qrow] = lrun[j];
        }
    }
#undef STAGE
}

// ---------------- gate loss: 4 waves/block, one (b,s) per wave ----------------
__global__ void loss_kernel(const float* __restrict__ gtraw, const float* __restrict__ mfin,
                            const float* __restrict__ lfin, const float* __restrict__ qgp,
                            const float* __restrict__ kgp, float* __restrict__ out_loss) {
    int wid = threadIdx.x >> 6, lane = threadIdx.x & 63;
    int blk = blockIdx.x * 4 + wid;     // b*(S/2) + (s-512)
    int b = blk >> 9, s = 512 + (blk & 511);
    int kv = lane >> 4, n = lane & 15;
    int nvis = (s >> 6) + 1;
    float tn = 0.f;
    if (n < nvis) {
        for (int g = 0; g < 4; g++) {
            int h = kv * 4 + g;
            long idx = ((long)b * H_ + h) * S_ + s;
            float gt = __expf(gtraw[idx * NB_ + n] - mfin[idx]) / lfin[idx];
            tn = fmaxf(tn, gt);
        }
    }
    float tsum = tn;
    for (int m = 1; m < 16; m <<= 1) tsum += __shfl_xor(tsum, m);
    tn = tn / (tsum + 1e-9f);
    float z = -INFINITY;
    if (n < nvis) {
        const float* qv = qgp + (((long)b * S_ + s) * HKV_ + kv) * GH_;
        const float* kvp = kgp + (((long)b * NB_ + n) * HKV_ + kv) * GH_;
        float acc = 0.f;
        for (int d = 0; d < GH_; d++) acc += qv[d] * kvp[d];
        z = acc * SCALE_;
    }
    float zmax = z;
    for (int m = 1; m < 16; m <<= 1) zmax = fmaxf(zmax, __shfl_xor(zmax, m));
    float ez = (n < nvis) ? __expf(z - zmax) : 0.f;
    float se = ez;
    for (int m = 1; m < 16; m <<= 1) se += __shfl_xor(se, m);
    float logZ = zmax + __logf(se);
    float kl = 0.f;
    if (tn > 0.f) kl = tn * (__logf(tn) - (z - logZ));
    for (int m = 1; m < 16; m <<= 1) kl += __shfl_xor(kl, m);
    kl += __shfl_xor(kl, 16);
    kl += __shfl_xor(kl, 32);
    __shared__ float part[4];
    if (lane == 0) part[wid] = kl;
    __syncthreads();
    if (threadIdx.x == 0)
        atomicAdd(out_loss, (part[0] + part[1] + part[2] + part[3]) * (1.0f / 65536.0f));
}

extern "C" void kernel_launch(void* const* d_in, const int* in_sizes, int n_in,
                              void* d_out, int out_size, void* d_ws, size_t ws_size,
                              hipStream_t stream) {
    const float* hs    = (const float*)d_in[0];
    const float* wq    = (const float*)d_in[1];
    const float* wk    = (const float*)d_in[2];
    const float* wv    = (const float*)d_in[3];
    const float* wo    = (const float*)d_in[4];
    const float* qnw   = (const float*)d_in[5];
    const float* knw   = (const float*)d_in[6];
    const float* gwq   = (const float*)d_in[7];
    const float* gwk   = (const float*)d_in[8];
    const float* cosp  = (const float*)d_in[9];
    const float* sinp  = (const float*)d_in[10];
    const float* cosgq = (const float*)d_in[11];
    const float* singq = (const float*)d_in[12];
    const float* cosb  = (const float*)d_in[13];
    const float* sinb  = (const float*)d_in[14];
    // d_in[15] (block_attention_mask) is deterministic: n*64 <= s — never read.

    char* ws = (char*)d_ws;
    size_t off = 0;
    auto alloc = [&](size_t bytes) { void* p = ws + off; off += (bytes + 255) & ~255ULL; return p; };
    u16*  hsb    = (u16*)alloc((size_t)M_ * DM_ * 2);       // 8MB; dead after QKV gemm -> reused as attnb
    u16*  wqkvT  = (u16*)alloc(3072UL * 2048 * 2);          // 12MB combined [wqT; wkT; wvT]
    u16*  woT    = (u16*)alloc(2048UL * 2048 * 2);          // 8MB
    u16*  qkvb   = (u16*)alloc((size_t)M_ * 3072 * 2);      // 12MB bf16 QKV output
    u16*  qrb    = (u16*)alloc(2048UL * 2048 * 2);
    u16*  krb    = (u16*)alloc(2048UL * 512 * 2);
    u16*  knb    = (u16*)alloc(2048UL * 512 * 2);
    u16*  vtb    = (u16*)alloc(8UL * 128 * 1024 * 2);
    float* qgp   = (float*)alloc(2048UL * 4 * 128 * 4);
    float* kgp   = (float*)alloc(2UL * 16 * 4 * 128 * 4);
    float* gtraw = (float*)alloc(2UL * 16 * 1024 * 16 * 4);
    float* mfin  = (float*)alloc(2UL * 16 * 1024 * 4);
    float* lfin  = (float*)alloc(2UL * 16 * 1024 * 4);
    u16*  attnb  = hsb;                                     // alias: hsb dead before attn writes

    float* out = (float*)d_out;
    float* loss_slot = out + (size_t)M_ * DM_;

    cvt_kernel<<<1024, 256, 0, stream>>>(hs, hsb, M_ * DM_);
    wtrans_all_kernel<<<dim3(160, 64), 256, 0, stream>>>(wq, wk, wv, wo, wqkvT, woT);

    // fused QKV projection: [2048][2048] @ [2048][3072] -> bf16 [2048][3072]
    gemm_bf16_kernel<<<dim3(24, 16), 256, 0, stream>>>(hsb, wqkvT, nullptr, qkvb, 3072, 2048);

    normrope_kernel<<<2048, 256, 0, stream>>>(qkvb, qnw, knw, cosp, sinp, cosgq, singq, gwq,
                                              qrb, krb, knb, qgp);
    vtrans_kernel<<<dim3(4, 32, 8), 256, 0, stream>>>(qkvb, vtb);
    kp_kernel<<<128, 128, 0, stream>>>(knb, cosb, sinb, gwk, kgp, loss_slot);

    attn_kernel<<<512, 256, 0, stream>>>(qrb, krb, vtb, attnb, gtraw, mfin, lfin);
    loss_kernel<<<256, 256, 0, stream>>>(gtraw, mfin, lfin, qgp, kgp, loss_slot);

    // output projection: [2048][2048]bf16 @ [2048][2048] -> f32 out
    gemm_bf16_kernel<<<dim3(16, 16), 256, 0, stream>>>(attnb, woT, out, nullptr, 2048, 2048);
}

// Round 5
// 258.765 us; speedup vs baseline: 1.3068x; 1.0256x over previous
//
#include <hip/hip_runtime.h>

typedef unsigned short u16;
typedef unsigned int u32;
typedef __attribute__((ext_vector_type(8))) short bf16x8;
typedef __attribute__((ext_vector_type(4))) float f32x4;

#define DEV static __device__ __forceinline__

constexpr int B_ = 2, S_ = 1024, DM_ = 2048, H_ = 16, HKV_ = 4, DH_ = 128, NB_ = 16, BLK_ = 64, GH_ = 128;
constexpr int M_ = B_ * S_;                 // 2048 token rows
constexpr float EPS_ = 1e-6f;
constexpr float SCALE_ = 0.08838834764831845f;   // 1/sqrt(128); also gate scale (GH=128)

DEV u16 f2bf(float f) {
    u32 u = __float_as_uint(f);
    u += 0x7fffu + ((u >> 16) & 1u);
    return (u16)(u >> 16);
}
DEV float bf2f(u16 h) { return __uint_as_float(((u32)h) << 16); }

// async global->LDS, 16B per lane. LDS dest is wave-uniform base (+lane*16 implicit).
DEV void gload16(const void* g, void* l) {
    __builtin_amdgcn_global_load_lds((const __attribute__((address_space(1))) void*)g,
                                     (__attribute__((address_space(3))) void*)l, 16, 0, 0);
}

// ---------------- f32 -> bf16 convert (vectorized) ----------------
__global__ void cvt_kernel(const float* __restrict__ in, u16* __restrict__ out, int n) {
    int i = (blockIdx.x * blockDim.x + threadIdx.x) * 4;
    int stride = gridDim.x * blockDim.x * 4;
    for (; i < n; i += stride) {
        float4 v = *reinterpret_cast<const float4*>(in + i);
        uint2 o;
        o.x = (u32)f2bf(v.x) | ((u32)f2bf(v.y) << 16);
        o.y = (u32)f2bf(v.z) | ((u32)f2bf(v.w) << 16);
        *reinterpret_cast<uint2*>(out + i) = o;
    }
}

// ---------------- fused weight transpose+convert: wq/wk/wv -> wqkvT, wo -> woT ----------------
__global__ void wtrans_all_kernel(const float* __restrict__ wq, const float* __restrict__ wk,
                                  const float* __restrict__ wv, const float* __restrict__ wo,
                                  u16* __restrict__ wqkvT, u16* __restrict__ woT) {
    __shared__ float tile[32][33];
    int bx = blockIdx.x;
    const float* in; u16* out; int Cc, c0;
    if (bx < 64)      { in = wq; out = wqkvT;                 Cc = 2048; c0 = bx * 32; }
    else if (bx < 80) { in = wk; out = wqkvT + 2048UL * 2048; Cc = 512;  c0 = (bx - 64) * 32; }
    else if (bx < 96) { in = wv; out = wqkvT + 2560UL * 2048; Cc = 512;  c0 = (bx - 80) * 32; }
    else              { in = wo; out = woT;                   Cc = 2048; c0 = (bx - 96) * 32; }
    int r0 = blockIdx.y * 32;
    int tx = threadIdx.x & 31, ty = threadIdx.x >> 5;   // 256 threads
    for (int i = 0; i < 4; i++) {
        int r = ty + i * 8;
        tile[r][tx] = in[(long)(r0 + r) * Cc + c0 + tx];
    }
    __syncthreads();
    for (int i = 0; i < 4; i++) {
        int r = ty + i * 8;
        out[(long)(c0 + r) * 2048 + r0 + tx] = f2bf(tile[tx][r]);
    }
}

// ---------------- V transpose: qkv bf16 [b*S][3072] (v at col 2560) -> vt bf16 [b][kv][DH][S] ----------------
__global__ void vtrans_kernel(const u16* __restrict__ qkv, u16* __restrict__ vt) {
    __shared__ u16 tile[32][34];
    int z = blockIdx.z;                 // b*HKV + kv
    int b = z >> 2, kv = z & 3;
    int c0 = blockIdx.x * 32;           // feature 0..127
    int r0 = blockIdx.y * 32;           // s 0..1023
    int tx = threadIdx.x & 31, ty = threadIdx.x >> 5;
    const u16* ip = qkv + (long)b * S_ * 3072 + 2560 + kv * DH_;
    for (int i = 0; i < 4; i++) {
        int r = ty + i * 8;
        tile[r][tx] = ip[(long)(r0 + r) * 3072 + c0 + tx];
    }
    __syncthreads();
    u16* op = vt + (long)z * DH_ * S_;
    for (int i = 0; i < 4; i++) {
        int r = ty + i * 8;
        op[(long)(c0 + r) * S_ + r0 + tx] = tile[tx][r];
    }
}

// ---------------- bf16 MFMA GEMM: double-buffered LDS + both-sides XOR swizzle + XCD grid swizzle ----------------
// LDS tile logical [128 rows][64 k] bf16, row stride 128B. Swizzle: u16 col ^= (row&7)<<3.
// Staged via gload_lds with INVERSE-swizzled global source col (rule #21).
__global__ __launch_bounds__(256, 2) void gemm_bf16_kernel(
    const u16* __restrict__ A, const u16* __restrict__ Bt,
    float* __restrict__ Cf, u16* __restrict__ Cb, int Nn, int Kk) {
    __shared__ u16 As[2][128 * 64];
    __shared__ u16 Bs[2][128 * 64];
    // XCD-aware bijective swizzle (nwg % 8 == 0 for all our grids)
    int bid = blockIdx.y * gridDim.x + blockIdx.x;
    int chunk = (gridDim.x * gridDim.y) >> 3;
    int sb = (bid & 7) * chunk + (bid >> 3);
    int m0 = (sb / gridDim.x) * 128, n0 = (sb % gridDim.x) * 128;
    int t = threadIdx.x;
    int wave = t >> 6, lane = t & 63;
    int wm = wave >> 1, wn = wave & 1;
    int lr = lane & 15, lg = lane >> 4;
    int srow = lane >> 3;
    int scol = (((lane & 7) * 8) ^ (srow << 3));        // u16 source col (inverse swizzle)
    int swz = (lr & 7) << 3;                            // u16 read swizzle
    f32x4 acc[4][4] = {};
#define GSTAGE(ktel, db)                                                       \
    {                                                                          \
        const u16* Ab = A + (long)m0 * Kk + (ktel);                            \
        const u16* Bb = Bt + (long)n0 * Kk + (ktel);                           \
        _Pragma("unroll")                                                      \
        for (int i = 0; i < 4; i++) {                                          \
            int c = wave * 4 + i;                                              \
            int row = c * 8 + srow;                                            \
            gload16(Ab + (long)row * Kk + scol, &As[db][c * 512]);             \
            gload16(Bb + (long)row * Kk + scol, &Bs[db][c * 512]);             \
        }                                                                      \
    }
    GSTAGE(0, 0);
    __syncthreads();
    int nk = Kk >> 6;
    for (int kt = 0; kt < nk; kt++) {
        int db = kt & 1;
        if (kt + 1 < nk) GSTAGE((kt + 1) << 6, db ^ 1);
#pragma unroll
        for (int kk = 0; kk < 64; kk += 32) {
            bf16x8 af[4], bfr[4];
            int kcol = (kk + lg * 8) ^ swz;
#pragma unroll
            for (int i = 0; i < 4; i++) {
                af[i]  = *reinterpret_cast<const bf16x8*>(&As[db][(wm * 64 + i * 16 + lr) * 64 + kcol]);
                bfr[i] = *reinterpret_cast<const bf16x8*>(&Bs[db][(wn * 64 + i * 16 + lr) * 64 + kcol]);
            }
            __builtin_amdgcn_s_setprio(1);
#pragma unroll
            for (int mi = 0; mi < 4; mi++)
#pragma unroll
                for (int ni = 0; ni < 4; ni++)
                    acc[mi][ni] = __builtin_amdgcn_mfma_f32_16x16x32_bf16(af[mi], bfr[ni], acc[mi][ni], 0, 0, 0);
            __builtin_amdgcn_s_setprio(0);
        }
        __syncthreads();
    }
#undef GSTAGE
    if (Cb) {
#pragma unroll
        for (int mi = 0; mi < 4; mi++)
#pragma unroll
            for (int ni = 0; ni < 4; ni++)
#pragma unroll
                for (int j = 0; j < 4; j++) {
                    int r = m0 + wm * 64 + mi * 16 + lg * 4 + j;
                    int c = n0 + wn * 64 + ni * 16 + lr;
                    Cb[(long)r * Nn + c] = f2bf(acc[mi][ni][j]);
                }
    } else {
#pragma unroll
        for (int mi = 0; mi < 4; mi++)
#pragma unroll
            for (int ni = 0; ni < 4; ni++)
#pragma unroll
                for (int j = 0; j < 4; j++) {
                    int r = m0 + wm * 64 + mi * 16 + lg * 4 + j;
                    int c = n0 + wn * 64 + ni * 16 + lr;
                    Cf[(long)r * Nn + c] = acc[mi][ni][j];
                }
    }
}

// ---------------- RMS norm + RoPE + qg/qgp (reads bf16 qkv: q cols 0..2047, k cols 2048..2559) ----------------
__global__ void normrope_kernel(
    const u16* __restrict__ qkv,
    const float* __restrict__ qw, const float* __restrict__ kw,
    const float* __restrict__ cosp, const float* __restrict__ sinp,
    const float* __restrict__ cosgq, const float* __restrict__ singq,
    const float* __restrict__ gate_wq,
    u16* __restrict__ qr, u16* __restrict__ kr, u16* __restrict__ kn,
    float* __restrict__ qgp) {
    int bs = blockIdx.x;
    int s = bs & (S_ - 1);
    int t = threadIdx.x;
    int w = t >> 6, lane = t & 63;
    __shared__ float qgl[HKV_][DH_];
    float c0 = cosp[s * DH_ + lane], c1 = cosp[s * DH_ + lane + 64];
    float s0 = sinp[s * DH_ + lane], s1 = sinp[s * DH_ + lane + 64];
    float qg0 = 0.f, qg1 = 0.f;
    const u16* qrow = qkv + (long)bs * 3072;
    for (int g = 0; g < 4; g++) {
        int h = w * 4 + g;
        float x0 = bf2f(qrow[h * DH_ + lane]), x1 = bf2f(qrow[h * DH_ + lane + 64]);
        float ss = x0 * x0 + x1 * x1;
        for (int m = 1; m < 64; m <<= 1) ss += __shfl_xor(ss, m);
        float r = rsqrtf(ss * (1.0f / DH_) + EPS_);
        float n0 = x0 * r * qw[lane], n1 = x1 * r * qw[lane + 64];
        qg0 += n0; qg1 += n1;
        u16* qrp = qr + (long)bs * (H_ * DH_) + h * DH_;
        qrp[lane]      = f2bf(n0 * c0 - n1 * s0);
        qrp[lane + 64] = f2bf(n1 * c1 + n0 * s1);
    }
    {
        const u16* krow = qkv + (long)bs * 3072 + 2048 + w * DH_;
        float x0 = bf2f(krow[lane]), x1 = bf2f(krow[lane + 64]);
        float ss = x0 * x0 + x1 * x1;
        for (int m = 1; m < 64; m <<= 1) ss += __shfl_xor(ss, m);
        float r = rsqrtf(ss * (1.0f / DH_) + EPS_);
        float n0 = x0 * r * kw[lane], n1 = x1 * r * kw[lane + 64];
        u16* knp = kn + (long)bs * (HKV_ * DH_) + w * DH_;
        knp[lane] = f2bf(n0); knp[lane + 64] = f2bf(n1);
        u16* krp = kr + (long)bs * (HKV_ * DH_) + w * DH_;
        krp[lane]      = f2bf(n0 * c0 - n1 * s0);
        krp[lane + 64] = f2bf(n1 * c1 + n0 * s1);
    }
    if (s >= S_ / 2) {    // qg/qgp only needed for the loss rows
        qg0 *= 0.25f; qg1 *= 0.25f;
        float cg0 = cosgq[s * DH_ + lane], cg1 = cosgq[s * DH_ + lane + 64];
        float sg0 = singq[s * DH_ + lane], sg1 = singq[s * DH_ + lane + 64];
        qgl[w][lane]      = qg0 * cg0 - qg1 * sg0;
        qgl[w][lane + 64] = qg1 * cg1 + qg0 * sg1;
        __syncthreads();
        for (int rep = 0; rep < 2; rep++) {
            int kv = (t >> 7) + rep * 2;
            int e = t & 127;
            float acc = 0.f;
            const float* qv = qgl[kv];
            for (int d = 0; d < DH_; d++) acc += qv[d] * gate_wq[d * GH_ + e];
            qgp[((long)bs * HKV_ + kv) * GH_ + e] = acc;
        }
    }
}

// ---------------- kp / kgp (+ zero the loss slot) ----------------
__global__ void kp_kernel(const u16* __restrict__ kn, const float* __restrict__ cosb,
                          const float* __restrict__ sinb, const float* __restrict__ gate_wk,
                          float* __restrict__ kgp, float* __restrict__ loss_slot) {
    int z = blockIdx.x;                 // (b*NB + n)*HKV + kv
    int kv = z & 3, n = (z >> 2) & 15, b = z >> 6;
    int d = threadIdx.x;                // 128 threads
    __shared__ float kp[DH_], kpr[DH_];
    float acc = 0.f;
    const u16* base = kn + (((long)b * S_ + n * BLK_) * HKV_ + kv) * DH_ + d;
    for (int i = 0; i < BLK_; i++) acc += bf2f(base[(long)i * HKV_ * DH_]);
    kp[d] = acc * (1.0f / BLK_);
    __syncthreads();
    float rot = (d < 64) ? -kp[d + 64] : kp[d - 64];
    kpr[d] = kp[d] * cosb[n * DH_ + d] + rot * sinb[n * DH_ + d];
    __syncthreads();
    float a2 = 0.f;
    for (int dd = 0; dd < DH_; dd++) a2 += kpr[dd] * gate_wk[dd * GH_ + d];
    kgp[(long)z * GH_ + d] = a2;
    if (z == 0 && d == 0) *loss_slot = 0.0f;
}

// ---------------- flash attention + gt raw stats: causal-PAIRED q-tiles ----------------
// Block handles q-tiles {15-pair, pair}: every block does exactly 17 KV iterations.
// K logical (r in [0,64), k in [0,128)) stored at LDS byte r*256 + ((k*2) ^ ((r&7)<<4))
// V logical (r in [0,128), c in [0,64)) stored at LDS byte r*128 + ((c*2) ^ ((r&7)<<4))
__global__ __launch_bounds__(256, 2) void attn_kernel(
    const u16* __restrict__ qr, const u16* __restrict__ kr, const u16* __restrict__ vt,
    u16* __restrict__ attn_out, float* __restrict__ gtraw,
    float* __restrict__ mfin, float* __restrict__ lfin) {
    __shared__ u16 Ks[2][BLK_ * DH_];
    __shared__ u16 Vts[2][DH_ * BLK_];
    __shared__ u16 Ps[4][16][72];
    int blk = blockIdx.x;
    int pair = blk & 7, h = (blk >> 3) & 15, b = blk >> 7;
    int kv = h >> 2;
    int t = threadIdx.x, wave = t >> 6, lane = t & 63;
    int lr = lane & 15, lg = lane >> 4;
    const u16* kbase = kr + (((long)b * S_) * HKV_ + kv) * DH_;       // row stride 512
    const u16* vbase = vt + ((long)(b * HKV_ + kv)) * DH_ * S_;       // row stride 1024
    int krow = (lane >> 4), kseg = (lane & 15) * 16;   // K chunk: 4 rows x 256B
    int vrow = (lane >> 3), vseg = (lane & 7) * 16;    // V chunk: 8 rows x 128B
    int sw = (lr & 7) << 3;

#define STAGE(nt, dbuf)                                                                   \
    {                                                                                     \
        const u16* kb = kbase + (long)(nt) * 64 * 512;                                    \
        const u16* vb = vbase + (nt) * 64;                                                \
        u16* uK = &Ks[dbuf][0];                                                           \
        u16* uV = &Vts[dbuf][0];                                                          \
        _Pragma("unroll")                                                                 \
        for (int i = 0; i < 4; i++) {                                                     \
            int c = wave * 4 + i;                                                         \
            {                                                                             \
                int r = c * 4 + krow;                                                     \
                int col = (kseg ^ ((r & 7) << 4)) >> 1;                                   \
                gload16(kb + (long)r * 512 + col, uK + c * 512);                          \
            }                                                                             \
            {                                                                             \
                int r = c * 8 + vrow;                                                     \
                int col = (vseg ^ ((r & 7) << 4)) >> 1;                                   \
                gload16(vb + (long)r * 1024 + col, uV + c * 512);                         \
            }                                                                             \
        }                                                                                 \
    }

    for (int rep = 0; rep < 2; rep++) {
        int qt = rep ? pair : 15 - pair;
        int q0 = qt * 64;
        bf16x8 qfr[4];
        {
            long qbase = (((long)b * S_ + q0 + wave * 16 + lr) * H_ + h) * DH_;
#pragma unroll
            for (int ko = 0; ko < 4; ko++)
                qfr[ko] = *reinterpret_cast<const bf16x8*>(qr + qbase + ko * 32 + lg * 8);
        }
        f32x4 acco[8] = {};
        float mrun[4], lrun[4];
#pragma unroll
        for (int j = 0; j < 4; j++) { mrun[j] = -INFINITY; lrun[j] = 0.f; }

        STAGE(0, 0);
        __syncthreads();   // drains vmcnt: tile 0 staged

        for (int n = 0; n <= qt; n++) {
            int d = n & 1;
            if (n < qt) STAGE(n + 1, d ^ 1);     // prefetch overlaps this iteration's compute
            const u16* uK = &Ks[d][0];
            const u16* uV = &Vts[d][0];
            f32x4 sacc[4] = {};
            __builtin_amdgcn_s_setprio(1);
#pragma unroll
            for (int ni = 0; ni < 4; ni++) {
                int rr = ni * 16 + lr;
#pragma unroll
                for (int ko = 0; ko < 4; ko++) {
                    bf16x8 kfr = *reinterpret_cast<const bf16x8*>(uK + rr * 128 + ((ko * 32 + lg * 8) ^ sw));
                    sacc[ni] = __builtin_amdgcn_mfma_f32_16x16x32_bf16(qfr[ko], kfr, sacc[ni], 0, 0, 0);
                }
            }
            __builtin_amdgcn_s_setprio(0);
            float bm[4] = {-INFINITY, -INFINITY, -INFINITY, -INFINITY};
            float sval[4][4];
#pragma unroll
            for (int ni = 0; ni < 4; ni++) {
                int key = n * 64 + ni * 16 + lr;
#pragma unroll
                for (int j = 0; j < 4; j++) {
                    int qrow = q0 + wave * 16 + lg * 4 + j;
                    float v = sacc[ni][j] * SCALE_;
                    if (key > qrow) v = -INFINITY;
                    sval[ni][j] = v;
                    bm[j] = fmaxf(bm[j], v);
                }
            }
#pragma unroll
            for (int j = 0; j < 4; j++)
                for (int m = 1; m < 16; m <<= 1)
                    bm[j] = fmaxf(bm[j], __shfl_xor(bm[j], m));
            if (lr == 0) {
#pragma unroll
                for (int j = 0; j < 4; j++) {
                    int qrow = q0 + wave * 16 + lg * 4 + j;
                    gtraw[(((long)b * H_ + h) * S_ + qrow) * NB_ + n] = bm[j];
                }
            }
            float cfac[4], rs[4];
#pragma unroll
            for (int j = 0; j < 4; j++) {
                float mnew = fmaxf(mrun[j], bm[j]);
                cfac[j] = __expf(mrun[j] - mnew);
                mrun[j] = mnew;
                rs[j] = 0.f;
            }
#pragma unroll
            for (int ni = 0; ni < 4; ni++)
#pragma unroll
                for (int j = 0; j < 4; j++) {
                    float p = __expf(sval[ni][j] - mrun[j]);
                    rs[j] += p;
                    Ps[wave][lg * 4 + j][ni * 16 + lr] = f2bf(p);
                }
#pragma unroll
            for (int j = 0; j < 4; j++) {
                float t2 = rs[j];
                for (int m = 1; m < 16; m <<= 1) t2 += __shfl_xor(t2, m);
                lrun[j] = lrun[j] * cfac[j] + t2;
            }
#pragma unroll
            for (int nf = 0; nf < 8; nf++)
#pragma unroll
                for (int j = 0; j < 4; j++) acco[nf][j] *= cfac[j];
            __builtin_amdgcn_s_setprio(1);
#pragma unroll
            for (int ko = 0; ko < 2; ko++) {
                bf16x8 pf = *reinterpret_cast<const bf16x8*>(&Ps[wave][lr][ko * 32 + lg * 8]);
#pragma unroll
                for (int nf = 0; nf < 8; nf++) {
                    int rr = nf * 16 + lr;
                    bf16x8 vf = *reinterpret_cast<const bf16x8*>(uV + rr * 64 + ((ko * 32 + lg * 8) ^ sw));
                    acco[nf] = __builtin_amdgcn_mfma_f32_16x16x32_bf16(pf, vf, acco[nf], 0, 0, 0);
                }
            }
            __builtin_amdgcn_s_setprio(0);
            __syncthreads();   // one barrier/iter: staged d^1 ready, reads of d done
        }
        float invl[4];
#pragma unroll
        for (int j = 0; j < 4; j++) invl[j] = 1.0f / lrun[j];
#pragma unroll
        for (int nf = 0; nf < 8; nf++)
#pragma unroll
            for (int j = 0; j < 4; j++) {
                int qrow = q0 + wave * 16 + lg * 4 + j;
                attn_out[((long)b * S_ + qrow) * (H_ * DH_) + h * DH_ + nf * 16 + lr] = f2bf(acco[nf][j] * invl[j]);
            }
        if (lr == 0) {
#pragma unroll
            for (int j = 0; j < 4; j++) {
                int qrow = q0 + wave * 16 + lg * 4 + j;
                mfin[((long)b * H_ + h) * S_ + qrow] = mrun[j];
                lfin[((long)b * H_ + h) * S_ + qrow] = lrun[j];
            }
        }
    }
#undef STAGE
}

// ---------------- gate loss: 4 waves/block, one (b,s) per wave ----------------
__global__ void loss_kernel(const float* __restrict__ gtraw, const float* __restrict__ mfin,
                            const float* __restrict__ lfin, const float* __restrict__ qgp,
                            const float* __restrict__ kgp, float* __restrict__ out_loss) {
    int wid = threadIdx.x >> 6, lane = threadIdx.x & 63;
    int blk = blockIdx.x * 4 + wid;     // b*(S/2) + (s-512)
    int b = blk >> 9, s = 512 + (blk & 511);
    int kv = lane >> 4, n = lane & 15;
    int nvis = (s >> 6) + 1;
    float tn = 0.f;
    if (n < nvis) {
        for (int g = 0; g < 4; g++) {
            int h = kv * 4 + g;
            long idx = ((long)b * H_ + h) * S_ + s;
            float gt = __expf(gtraw[idx * NB_ + n] - mfin[idx]) / lfin[idx];
            tn = fmaxf(tn, gt);
        }
    }
    float tsum = tn;
    for (int m = 1; m < 16; m <<= 1) tsum += __shfl_xor(tsum, m);
    tn = tn / (tsum + 1e-9f);
    float z = -INFINITY;
    if (n < nvis) {
        const float* qv = qgp + (((long)b * S_ + s) * HKV_ + kv) * GH_;
        const float* kvp = kgp + (((long)b * NB_ + n) * HKV_ + kv) * GH_;
        float acc = 0.f;
        for (int d = 0; d < GH_; d++) acc += qv[d] * kvp[d];
        z = acc * SCALE_;
    }
    float zmax = z;
    for (int m = 1; m < 16; m <<= 1) zmax = fmaxf(zmax, __shfl_xor(zmax, m));
    float ez = (n < nvis) ? __expf(z - zmax) : 0.f;
    float se = ez;
    for (int m = 1; m < 16; m <<= 1) se += __shfl_xor(se, m);
    float logZ = zmax + __logf(se);
    float kl = 0.f;
    if (tn > 0.f) kl = tn * (__logf(tn) - (z - logZ));
    for (int m = 1; m < 16; m <<= 1) kl += __shfl_xor(kl, m);
    kl += __shfl_xor(kl, 16);
    kl += __shfl_xor(kl, 32);
    __shared__ float part[4];
    if (lane == 0) part[wid] = kl;
    __syncthreads();
    if (threadIdx.x == 0)
        atomicAdd(out_loss, (part[0] + part[1] + part[2] + part[3]) * (1.0f / 65536.0f));
}

extern "C" void kernel_launch(void* const* d_in, const int* in_sizes, int n_in,
                              void* d_out, int out_size, void* d_ws, size_t ws_size,
                              hipStream_t stream) {
    const float* hs    = (const float*)d_in[0];
    const float* wq    = (const float*)d_in[1];
    const float* wk    = (const float*)d_in[2];
    const float* wv    = (const float*)d_in[3];
    const float* wo    = (const float*)d_in[4];
    const float* qnw   = (const float*)d_in[5];
    const float* knw   = (const float*)d_in[6];
    const float* gwq   = (const float*)d_in[7];
    const float* gwk   = (const float*)d_in[8];
    const float* cosp  = (const float*)d_in[9];
    const float* sinp  = (const float*)d_in[10];
    const float* cosgq = (const float*)d_in[11];
    const float* singq = (const float*)d_in[12];
    const float* cosb  = (const float*)d_in[13];
    const float* sinb  = (const float*)d_in[14];
    // d_in[15] (block_attention_mask) is deterministic: n*64 <= s — never read.

    char* ws = (char*)d_ws;
    size_t off = 0;
    auto alloc = [&](size_t bytes) { void* p = ws + off; off += (bytes + 255) & ~255ULL; return p; };
    u16*  hsb    = (u16*)alloc((size_t)M_ * DM_ * 2);       // 8MB; dead after QKV gemm -> reused as attnb
    u16*  wqkvT  = (u16*)alloc(3072UL * 2048 * 2);          // 12MB combined [wqT; wkT; wvT]
    u16*  woT    = (u16*)alloc(2048UL * 2048 * 2);          // 8MB
    u16*  qkvb   = (u16*)alloc((size_t)M_ * 3072 * 2);      // 12MB bf16 QKV output
    u16*  qrb    = (u16*)alloc(2048UL * 2048 * 2);
    u16*  krb    = (u16*)alloc(2048UL * 512 * 2);
    u16*  knb    = (u16*)alloc(2048UL * 512 * 2);
    u16*  vtb    = (u16*)alloc(8UL * 128 * 1024 * 2);
    float* qgp   = (float*)alloc(2048UL * 4 * 128 * 4);
    float* kgp   = (float*)alloc(2UL * 16 * 4 * 128 * 4);
    float* gtraw = (float*)alloc(2UL * 16 * 1024 * 16 * 4);
    float* mfin  = (float*)alloc(2UL * 16 * 1024 * 4);
    float* lfin  = (float*)alloc(2UL * 16 * 1024 * 4);
    u16*  attnb  = hsb;                                     // alias: hsb dead before attn writes

    float* out = (float*)d_out;
    float* loss_slot = out + (size_t)M_ * DM_;

    cvt_kernel<<<1024, 256, 0, stream>>>(hs, hsb, M_ * DM_);
    wtrans_all_kernel<<<dim3(160, 64), 256, 0, stream>>>(wq, wk, wv, wo, wqkvT, woT);

    // fused QKV projection: [2048][2048] @ [2048][3072] -> bf16 [2048][3072]
    gemm_bf16_kernel<<<dim3(24, 16), 256, 0, stream>>>(hsb, wqkvT, nullptr, qkvb, 3072, 2048);

    normrope_kernel<<<2048, 256, 0, stream>>>(qkvb, qnw, knw, cosp, sinp, cosgq, singq, gwq,
                                              qrb, krb, knb, qgp);
    vtrans_kernel<<<dim3(4, 32, 8), 256, 0, stream>>>(qkvb, vtb);
    kp_kernel<<<128, 128, 0, stream>>>(knb, cosb, sinb, gwk, kgp, loss_slot);

    // paired-causal flash attention: 256 balanced blocks
    attn_kernel<<<256, 256, 0, stream>>>(qrb, krb, vtb, attnb, gtraw, mfin, lfin);
    loss_kernel<<<256, 256, 0, stream>>>(gtraw, mfin, lfin, qgp, kgp, loss_slot);

    // output projection: [2048][2048]bf16 @ [2048][2048] -> f32 out
    gemm_bf16_kernel<<<dim3(16, 16), 256, 0, stream>>>(attnb, woT, out, nullptr, 2048, 2048);
}

// Round 7
// 248.824 us; speedup vs baseline: 1.3590x; 1.0399x over previous
//
#include <hip/hip_runtime.h>

typedef unsigned short u16;
typedef unsigned int u32;
typedef __attribute__((ext_vector_type(8))) short bf16x8;
typedef __attribute__((ext_vector_type(4))) float f32x4;

#define DEV static __device__ __forceinline__

constexpr int B_ = 2, S_ = 1024, DM_ = 2048, H_ = 16, HKV_ = 4, DH_ = 128, NB_ = 16, BLK_ = 64, GH_ = 128;
constexpr int M_ = B_ * S_;                 // 2048 token rows
constexpr float EPS_ = 1e-6f;
constexpr float SCALE_ = 0.08838834764831845f;   // 1/sqrt(128); also gate scale (GH=128)

DEV u16 f2bf(float f) {
    u32 u = __float_as_uint(f);
    u += 0x7fffu + ((u >> 16) & 1u);
    return (u16)(u >> 16);
}
DEV float bf2f(u16 h) { return __uint_as_float(((u32)h) << 16); }

// async global->LDS, 16B per lane. LDS dest is wave-uniform base (+lane*16 implicit).
DEV void gload16(const void* g, void* l) {
    __builtin_amdgcn_global_load_lds((const __attribute__((address_space(1))) void*)g,
                                     (__attribute__((address_space(3))) void*)l, 16, 0, 0);
}

// ---------------- prep: f32->bf16 convert (blocks 0..1023) + weight transposes (blocks 1024..11263) ----------------
__global__ void prep_kernel(const float* __restrict__ hs,
                            const float* __restrict__ wq, const float* __restrict__ wk,
                            const float* __restrict__ wv, const float* __restrict__ wo,
                            u16* __restrict__ hsb, u16* __restrict__ wqkvT, u16* __restrict__ woT) {
    __shared__ float tile[32][33];
    int blk = blockIdx.x;
    if (blk < 1024) {   // cvt hs -> hsb
        int n = M_ * DM_;
        int i = (blk * 256 + threadIdx.x) * 4;
        int stride = 1024 * 256 * 4;
        for (; i < n; i += stride) {
            float4 v = *reinterpret_cast<const float4*>(hs + i);
            uint2 o;
            o.x = (u32)f2bf(v.x) | ((u32)f2bf(v.y) << 16);
            o.y = (u32)f2bf(v.z) | ((u32)f2bf(v.w) << 16);
            *reinterpret_cast<uint2*>(hsb + i) = o;
        }
        return;
    }
    int idx = blk - 1024;
    int bx = idx % 160, by = idx / 160;     // 160 x 64
    const float* in; u16* out; int Cc, c0;
    if (bx < 64)      { in = wq; out = wqkvT;                 Cc = 2048; c0 = bx * 32; }
    else if (bx < 80) { in = wk; out = wqkvT + 2048UL * 2048; Cc = 512;  c0 = (bx - 64) * 32; }
    else if (bx < 96) { in = wv; out = wqkvT + 2560UL * 2048; Cc = 512;  c0 = (bx - 80) * 32; }
    else              { in = wo; out = woT;                   Cc = 2048; c0 = (bx - 96) * 32; }
    int r0 = by * 32;
    int tx = threadIdx.x & 31, ty = threadIdx.x >> 5;   // 256 threads
    for (int i = 0; i < 4; i++) {
        int r = ty + i * 8;
        tile[r][tx] = in[(long)(r0 + r) * Cc + c0 + tx];
    }
    __syncthreads();
    for (int i = 0; i < 4; i++) {
        int r = ty + i * 8;
        out[(long)(c0 + r) * 2048 + r0 + tx] = f2bf(tile[tx][r]);
    }
}

// ---------------- bf16 MFMA GEMM (QKV): double-buffered LDS + both-sides XOR swizzle + XCD grid swizzle ----------------
__global__ __launch_bounds__(256, 2) void gemm_bf16_kernel(
    const u16* __restrict__ A, const u16* __restrict__ Bt,
    u16* __restrict__ Cb, int Nn, int Kk) {
    __shared__ u16 As[2][128 * 64];
    __shared__ u16 Bs[2][128 * 64];
    int bid = blockIdx.y * gridDim.x + blockIdx.x;
    int chunk = (gridDim.x * gridDim.y) >> 3;
    int sb = (bid & 7) * chunk + (bid >> 3);
    int m0 = (sb / gridDim.x) * 128, n0 = (sb % gridDim.x) * 128;
    int t = threadIdx.x;
    int wave = t >> 6, lane = t & 63;
    int wm = wave >> 1, wn = wave & 1;
    int lr = lane & 15, lg = lane >> 4;
    int srow = lane >> 3;
    int scol = (((lane & 7) * 8) ^ (srow << 3));        // u16 source col (inverse swizzle)
    int swz = (lr & 7) << 3;                            // u16 read swizzle
    f32x4 acc[4][4] = {};
#define GSTAGE(ktel, db)                                                       \
    {                                                                          \
        const u16* Ab = A + (long)m0 * Kk + (ktel);                            \
        const u16* Bb = Bt + (long)n0 * Kk + (ktel);                           \
        _Pragma("unroll")                                                      \
        for (int i = 0; i < 4; i++) {                                          \
            int c = wave * 4 + i;                                              \
            int row = c * 8 + srow;                                            \
            gload16(Ab + (long)row * Kk + scol, &As[db][c * 512]);             \
            gload16(Bb + (long)row * Kk + scol, &Bs[db][c * 512]);             \
        }                                                                      \
    }
    GSTAGE(0, 0);
    __syncthreads();
    int nk = Kk >> 6;
    for (int kt = 0; kt < nk; kt++) {
        int db = kt & 1;
        if (kt + 1 < nk) GSTAGE((kt + 1) << 6, db ^ 1);
#pragma unroll
        for (int kk = 0; kk < 64; kk += 32) {
            bf16x8 af[4], bfr[4];
            int kcol = (kk + lg * 8) ^ swz;
#pragma unroll
            for (int i = 0; i < 4; i++) {
                af[i]  = *reinterpret_cast<const bf16x8*>(&As[db][(wm * 64 + i * 16 + lr) * 64 + kcol]);
                bfr[i] = *reinterpret_cast<const bf16x8*>(&Bs[db][(wn * 64 + i * 16 + lr) * 64 + kcol]);
            }
            __builtin_amdgcn_s_setprio(1);
#pragma unroll
            for (int mi = 0; mi < 4; mi++)
#pragma unroll
                for (int ni = 0; ni < 4; ni++)
                    acc[mi][ni] = __builtin_amdgcn_mfma_f32_16x16x32_bf16(af[mi], bfr[ni], acc[mi][ni], 0, 0, 0);
            __builtin_amdgcn_s_setprio(0);
        }
        __syncthreads();
    }
#undef GSTAGE
#pragma unroll
    for (int mi = 0; mi < 4; mi++)
#pragma unroll
        for (int ni = 0; ni < 4; ni++)
#pragma unroll
            for (int j = 0; j < 4; j++) {
                int r = m0 + wm * 64 + mi * 16 + lg * 4 + j;
                int c = n0 + wn * 64 + ni * 16 + lr;
                Cb[(long)r * Nn + c] = f2bf(acc[mi][ni][j]);
            }
}

// ---------------- normrope (blocks 0..2047) + V transpose (blocks 2048..3071) ----------------
__global__ void nrvt_kernel(
    const u16* __restrict__ qkv,
    const float* __restrict__ qw, const float* __restrict__ kw,
    const float* __restrict__ cosp, const float* __restrict__ sinp,
    const float* __restrict__ cosgq, const float* __restrict__ singq,
    const float* __restrict__ gate_wq,
    u16* __restrict__ qr, u16* __restrict__ kr, u16* __restrict__ kn,
    float* __restrict__ qgp, u16* __restrict__ vt) {
    __shared__ float qgl[HKV_][DH_];
    __shared__ u16 tile[32][34];
    int blk = blockIdx.x;
    int t = threadIdx.x;
    if (blk >= 2048) {      // V transpose: qkv [b*S][3072] (v at 2560) -> vt [b][kv][DH][S]
        int idx = blk - 2048;
        int x = idx & 3, y = (idx >> 2) & 31, z = idx >> 7;   // z = b*HKV+kv
        int c0 = x * 32, r0 = y * 32;
        int tx = t & 31, ty = t >> 5;
        const u16* ip = qkv + (long)(z >> 2) * S_ * 3072 + 2560 + (z & 3) * DH_;
        for (int i = 0; i < 4; i++) {
            int r = ty + i * 8;
            tile[r][tx] = ip[(long)(r0 + r) * 3072 + c0 + tx];
        }
        __syncthreads();
        u16* op = vt + (long)z * DH_ * S_;
        for (int i = 0; i < 4; i++) {
            int r = ty + i * 8;
            op[(long)(c0 + r) * S_ + r0 + tx] = tile[tx][r];
        }
        return;
    }
    int bs = blk;
    int s = bs & (S_ - 1);
    int w = t >> 6, lane = t & 63;
    float c0 = cosp[s * DH_ + lane], c1 = cosp[s * DH_ + lane + 64];
    float s0 = sinp[s * DH_ + lane], s1 = sinp[s * DH_ + lane + 64];
    float qg0 = 0.f, qg1 = 0.f;
    const u16* qrow = qkv + (long)bs * 3072;
    for (int g = 0; g < 4; g++) {
        int h = w * 4 + g;
        float x0 = bf2f(qrow[h * DH_ + lane]), x1 = bf2f(qrow[h * DH_ + lane + 64]);
        float ss = x0 * x0 + x1 * x1;
        for (int m = 1; m < 64; m <<= 1) ss += __shfl_xor(ss, m);
        float r = rsqrtf(ss * (1.0f / DH_) + EPS_);
        float n0 = x0 * r * qw[lane], n1 = x1 * r * qw[lane + 64];
        qg0 += n0; qg1 += n1;
        u16* qrp = qr + (long)bs * (H_ * DH_) + h * DH_;
        qrp[lane]      = f2bf(n0 * c0 - n1 * s0);
        qrp[lane + 64] = f2bf(n1 * c1 + n0 * s1);
    }
    {
        const u16* krow = qkv + (long)bs * 3072 + 2048 + w * DH_;
        float x0 = bf2f(krow[lane]), x1 = bf2f(krow[lane + 64]);
        float ss = x0 * x0 + x1 * x1;
        for (int m = 1; m < 64; m <<= 1) ss += __shfl_xor(ss, m);
        float r = rsqrtf(ss * (1.0f / DH_) + EPS_);
        float n0 = x0 * r * kw[lane], n1 = x1 * r * kw[lane + 64];
        u16* knp = kn + (long)bs * (HKV_ * DH_) + w * DH_;
        knp[lane] = f2bf(n0); knp[lane + 64] = f2bf(n1);
        u16* krp = kr + (long)bs * (HKV_ * DH_) + w * DH_;
        krp[lane]      = f2bf(n0 * c0 - n1 * s0);
        krp[lane + 64] = f2bf(n1 * c1 + n0 * s1);
    }
    if (s >= S_ / 2) {    // qg/qgp only needed for the loss rows
        qg0 *= 0.25f; qg1 *= 0.25f;
        float cg0 = cosgq[s * DH_ + lane], cg1 = cosgq[s * DH_ + lane + 64];
        float sg0 = singq[s * DH_ + lane], sg1 = singq[s * DH_ + lane + 64];
        qgl[w][lane]      = qg0 * cg0 - qg1 * sg0;
        qgl[w][lane + 64] = qg1 * cg1 + qg0 * sg1;
        __syncthreads();
        for (int rep = 0; rep < 2; rep++) {
            int kv = (t >> 7) + rep * 2;
            int e = t & 127;
            float acc = 0.f;
            const float* qv = qgl[kv];
            for (int d = 0; d < DH_; d++) acc += qv[d] * gate_wq[d * GH_ + e];
            qgp[((long)bs * HKV_ + kv) * GH_ + e] = acc;
        }
    }
}

// ---------------- flash attention (blocks 0..511, descending-qt dispatch) + kp/kgp (blocks 512..639) ----------------
// K logical (r,k) at LDS byte r*256 + ((k*2) ^ ((r&7)<<4)); V logical (r,c) at r*128 + ((c*2) ^ ((r&7)<<4))
__global__ __launch_bounds__(256, 2) void attn_kp_kernel(
    const u16* __restrict__ qr, const u16* __restrict__ kr, const u16* __restrict__ vt,
    u16* __restrict__ attn_out, float* __restrict__ gtraw,
    float* __restrict__ mfin, float* __restrict__ lfin,
    const u16* __restrict__ kn, const float* __restrict__ cosb,
    const float* __restrict__ sinb, const float* __restrict__ gate_wk,
    float* __restrict__ kgp, float* __restrict__ loss_slot) {
    __shared__ u16 Ks[2][BLK_ * DH_];
    __shared__ u16 Vts[2][DH_ * BLK_];
    __shared__ u16 Ps[4][16][72];
    __shared__ float kpm[DH_], kpr[DH_];
    int blk = blockIdx.x;
    int t = threadIdx.x;
    if (blk >= 512) {   // ---- kp/kgp part ----
        int z = blk - 512;              // (b*NB + n)*HKV + kv
        int kv = z & 3, n = (z >> 2) & 15, b = z >> 6;
        int d = t & 127;
        bool act = t < 128;
        if (act) {
            float acc = 0.f;
            const u16* base = kn + (((long)b * S_ + n * BLK_) * HKV_ + kv) * DH_ + d;
            for (int i = 0; i < BLK_; i++) acc += bf2f(base[(long)i * HKV_ * DH_]);
            kpm[d] = acc * (1.0f / BLK_);
        }
        __syncthreads();
        if (act) {
            float rot = (d < 64) ? -kpm[d + 64] : kpm[d - 64];
            kpr[d] = kpm[d] * cosb[n * DH_ + d] + rot * sinb[n * DH_ + d];
        }
        __syncthreads();
        if (act) {
            float a2 = 0.f;
            for (int dd = 0; dd < DH_; dd++) a2 += kpr[dd] * gate_wk[dd * GH_ + d];
            kgp[(long)z * GH_ + d] = a2;
        }
        if (z == 0 && t == 0) *loss_slot = 0.0f;
        return;
    }
    // ---- attention part: qt descending with blk so long blocks dispatch first ----
    int qt = 15 - (blk >> 5);
    int bh = blk & 31, b = bh >> 4, h = bh & 15;
    int kv = h >> 2;
    int wave = t >> 6, lane = t & 63;
    int lr = lane & 15, lg = lane >> 4;
    int q0 = qt * 64;
    const u16* kbase = kr + (((long)b * S_) * HKV_ + kv) * DH_;       // row stride 512
    const u16* vbase = vt + ((long)(b * HKV_ + kv)) * DH_ * S_;       // row stride 1024
    bf16x8 qfr[4];
    {
        long qbase = (((long)b * S_ + q0 + wave * 16 + lr) * H_ + h) * DH_;
#pragma unroll
        for (int ko = 0; ko < 4; ko++)
            qfr[ko] = *reinterpret_cast<const bf16x8*>(qr + qbase + ko * 32 + lg * 8);
    }
    f32x4 acco[8] = {};
    float mrun[4], lrun[4];
#pragma unroll
    for (int j = 0; j < 4; j++) { mrun[j] = -INFINITY; lrun[j] = 0.f; }
    int krow = (lane >> 4), kseg = (lane & 15) * 16;   // K chunk: 4 rows x 256B
    int vrow = (lane >> 3), vseg = (lane & 7) * 16;    // V chunk: 8 rows x 128B
    int sw = (lr & 7) << 3;

#define STAGE(nt, dbuf)                                                                   \
    {                                                                                     \
        const u16* kb = kbase + (long)(nt) * 64 * 512;                                    \
        const u16* vb = vbase + (nt) * 64;                                                \
        u16* uK = &Ks[dbuf][0];                                                           \
        u16* uV = &Vts[dbuf][0];                                                          \
        _Pragma("unroll")                                                                 \
        for (int i = 0; i < 4; i++) {                                                     \
            int c = wave * 4 + i;                                                         \
            {                                                                             \
                int r = c * 4 + krow;                                                     \
                int col = (kseg ^ ((r & 7) << 4)) >> 1;                                   \
                gload16(kb + (long)r * 512 + col, uK + c * 512);                          \
            }                                                                             \
            {                                                                             \
                int r = c * 8 + vrow;                                                     \
                int col = (vseg ^ ((r & 7) << 4)) >> 1;                                   \
                gload16(vb + (long)r * 1024 + col, uV + c * 512);                         \
            }                                                                             \
        }                                                                                 \
    }

    STAGE(0, 0);
    __syncthreads();   // drains vmcnt: tile 0 staged

    for (int n = 0; n <= qt; n++) {
        int d = n & 1;
        if (n < qt) STAGE(n + 1, d ^ 1);     // prefetch overlaps this iteration's compute
        const u16* uK = &Ks[d][0];
        const u16* uV = &Vts[d][0];
        f32x4 sacc[4] = {};
        __builtin_amdgcn_s_setprio(1);
#pragma unroll
        for (int ni = 0; ni < 4; ni++) {
            int rr = ni * 16 + lr;
#pragma unroll
            for (int ko = 0; ko < 4; ko++) {
                bf16x8 kfr = *reinterpret_cast<const bf16x8*>(uK + rr * 128 + ((ko * 32 + lg * 8) ^ sw));
                sacc[ni] = __builtin_amdgcn_mfma_f32_16x16x32_bf16(qfr[ko], kfr, sacc[ni], 0, 0, 0);
            }
        }
        __builtin_amdgcn_s_setprio(0);
        float bm[4] = {-INFINITY, -INFINITY, -INFINITY, -INFINITY};
        float sval[4][4];
#pragma unroll
        for (int ni = 0; ni < 4; ni++) {
            int key = n * 64 + ni * 16 + lr;
#pragma unroll
            for (int j = 0; j < 4; j++) {
                int qrow = q0 + wave * 16 + lg * 4 + j;
                float v = sacc[ni][j] * SCALE_;
                if (key > qrow) v = -INFINITY;
                sval[ni][j] = v;
                bm[j] = fmaxf(bm[j], v);
            }
        }
#pragma unroll
        for (int j = 0; j < 4; j++)
            for (int m = 1; m < 16; m <<= 1)
                bm[j] = fmaxf(bm[j], __shfl_xor(bm[j], m));
        if (lr == 0) {
#pragma unroll
            for (int j = 0; j < 4; j++) {
                int qrow = q0 + wave * 16 + lg * 4 + j;
                gtraw[(((long)b * H_ + h) * S_ + qrow) * NB_ + n] = bm[j];
            }
        }
        float cfac[4], rs[4];
#pragma unroll
        for (int j = 0; j < 4; j++) {
            float mnew = fmaxf(mrun[j], bm[j]);
            cfac[j] = __expf(mrun[j] - mnew);
            mrun[j] = mnew;
            rs[j] = 0.f;
        }
#pragma unroll
        for (int ni = 0; ni < 4; ni++)
#pragma unroll
            for (int j = 0; j < 4; j++) {
                float p = __expf(sval[ni][j] - mrun[j]);
                rs[j] += p;
                Ps[wave][lg * 4 + j][ni * 16 + lr] = f2bf(p);
            }
#pragma unroll
        for (int j = 0; j < 4; j++) {
            float t2 = rs[j];
            for (int m = 1; m < 16; m <<= 1) t2 += __shfl_xor(t2, m);
            lrun[j] = lrun[j] * cfac[j] + t2;
        }
#pragma unroll
        for (int nf = 0; nf < 8; nf++)
#pragma unroll
            for (int j = 0; j < 4; j++) acco[nf][j] *= cfac[j];
        __builtin_amdgcn_s_setprio(1);
#pragma unroll
        for (int ko = 0; ko < 2; ko++) {
            bf16x8 pf = *reinterpret_cast<const bf16x8*>(&Ps[wave][lr][ko * 32 + lg * 8]);
#pragma unroll
            for (int nf = 0; nf < 8; nf++) {
                int rr = nf * 16 + lr;
                bf16x8 vf = *reinterpret_cast<const bf16x8*>(uV + rr * 64 + ((ko * 32 + lg * 8) ^ sw));
                acco[nf] = __builtin_amdgcn_mfma_f32_16x16x32_bf16(pf, vf, acco[nf], 0, 0, 0);
            }
        }
        __builtin_amdgcn_s_setprio(0);
        __syncthreads();   // one barrier/iter: staged d^1 ready, reads of d done
    }
#undef STAGE
    float invl[4];
#pragma unroll
    for (int j = 0; j < 4; j++) invl[j] = 1.0f / lrun[j];
#pragma unroll
    for (int nf = 0; nf < 8; nf++)
#pragma unroll
        for (int j = 0; j < 4; j++) {
            int qrow = q0 + wave * 16 + lg * 4 + j;
            attn_out[((long)b * S_ + qrow) * (H_ * DH_) + h * DH_ + nf * 16 + lr] = f2bf(acco[nf][j] * invl[j]);
        }
    if (lr == 0) {
#pragma unroll
        for (int j = 0; j < 4; j++) {
            int qrow = q0 + wave * 16 + lg * 4 + j;
            mfin[((long)b * H_ + h) * S_ + qrow] = mrun[j];
            lfin[((long)b * H_ + h) * S_ + qrow] = lrun[j];
        }
    }
}

// ---------------- O-projection GEMM (blocks 0..255) + gate loss (blocks 256..511) ----------------
__global__ __launch_bounds__(256, 2) void oproj_loss_kernel(
    const u16* __restrict__ A, const u16* __restrict__ Bt, float* __restrict__ Cf,
    const float* __restrict__ gtraw, const float* __restrict__ mfin,
    const float* __restrict__ lfin, const float* __restrict__ qgp,
    const float* __restrict__ kgp, float* __restrict__ out_loss) {
    __shared__ u16 As[2][128 * 64];
    __shared__ u16 Bs[2][128 * 64];
    __shared__ float part[4];
    int blk = blockIdx.x;
    int t = threadIdx.x;
    if (blk >= 256) {   // ---- gate loss: 4 waves, one (b,s) per wave ----
        int wid = t >> 6, lane = t & 63;
        int lblk = (blk - 256) * 4 + wid;     // b*(S/2) + (s-512)
        int b = lblk >> 9, s = 512 + (lblk & 511);
        int kv = lane >> 4, n = lane & 15;
        int nvis = (s >> 6) + 1;
        float tn = 0.f;
        if (n < nvis) {
            for (int g = 0; g < 4; g++) {
                int h = kv * 4 + g;
                long idx = ((long)b * H_ + h) * S_ + s;
                float gt = __expf(gtraw[idx * NB_ + n] - mfin[idx]) / lfin[idx];
                tn = fmaxf(tn, gt);
            }
        }
        float tsum = tn;
        for (int m = 1; m < 16; m <<= 1) tsum += __shfl_xor(tsum, m);
        tn = tn / (tsum + 1e-9f);
        float z = -INFINITY;
        if (n < nvis) {
            const float* qv = qgp + (((long)b * S_ + s) * HKV_ + kv) * GH_;
            const float* kvp = kgp + (((long)b * NB_ + n) * HKV_ + kv) * GH_;
            float acc = 0.f;
            for (int d = 0; d < GH_; d++) acc += qv[d] * kvp[d];
            z = acc * SCALE_;
        }
        float zmax = z;
        for (int m = 1; m < 16; m <<= 1) zmax = fmaxf(zmax, __shfl_xor(zmax, m));
        float ez = (n < nvis) ? __expf(z - zmax) : 0.f;
        float se = ez;
        for (int m = 1; m < 16; m <<= 1) se += __shfl_xor(se, m);
        float logZ = zmax + __logf(se);
        float kl = 0.f;
        if (tn > 0.f) kl = tn * (__logf(tn) - (z - logZ));
        for (int m = 1; m < 16; m <<= 1) kl += __shfl_xor(kl, m);
        kl += __shfl_xor(kl, 16);
        kl += __shfl_xor(kl, 32);
        if (lane == 0) part[wid] = kl;
        __syncthreads();
        if (t == 0)
            atomicAdd(out_loss, (part[0] + part[1] + part[2] + part[3]) * (1.0f / 65536.0f));
        return;
    }
    // ---- O-projection GEMM: 2048x2048x2048, grid 16x16 + XCD swizzle ----
    constexpr int Nn = 2048, Kk = 2048;
    int sb = (blk & 7) * 32 + (blk >> 3);
    int m0 = (sb >> 4) * 128, n0 = (sb & 15) * 128;
    int wave = t >> 6, lane = t & 63;
    int wm = wave >> 1, wn = wave & 1;
    int lr = lane & 15, lg = lane >> 4;
    int srow = lane >> 3;
    int scol = (((lane & 7) * 8) ^ (srow << 3));
    int swz = (lr & 7) << 3;
    f32x4 acc[4][4] = {};
#define GSTAGE(ktel, db)                                                       \
    {                                                                          \
        const u16* Ab = A + (long)m0 * Kk + (ktel);                            \
        const u16* Bb = Bt + (long)n0 * Kk + (ktel);                           \
        _Pragma("unroll")                                                      \
        for (int i = 0; i < 4; i++) {                                          \
            int c = wave * 4 + i;                                              \
            int row = c * 8 + srow;                                            \
            gload16(Ab + (long)row * Kk + scol, &As[db][c * 512]);             \
            gload16(Bb + (long)row * Kk + scol, &Bs[db][c * 512]);             \
        }                                                                      \
    }
    GSTAGE(0, 0);
    __syncthreads();
    int nk = Kk >> 6;
    for (int kt = 0; kt < nk; kt++) {
        int db = kt & 1;
        if (kt + 1 < nk) GSTAGE((kt + 1) << 6, db ^ 1);
#pragma unroll
        for (int kk = 0; kk < 64; kk += 32) {
            bf16x8 af[4], bfr[4];
            int kcol = (kk + lg * 8) ^ swz;
#pragma unroll
            for (int i = 0; i < 4; i++) {
                af[i]  = *reinterpret_cast<const bf16x8*>(&As[db][(wm * 64 + i * 16 + lr) * 64 + kcol]);
                bfr[i] = *reinterpret_cast<const bf16x8*>(&Bs[db][(wn * 64 + i * 16 + lr) * 64 + kcol]);
            }
            __builtin_amdgcn_s_setprio(1);
#pragma unroll
            for (int mi = 0; mi < 4; mi++)
#pragma unroll
                for (int ni = 0; ni < 4; ni++)
                    acc[mi][ni] = __builtin_amdgcn_mfma_f32_16x16x32_bf16(af[mi], bfr[ni], acc[mi][ni], 0, 0, 0);
            __builtin_amdgcn_s_setprio(0);
        }
        __syncthreads();
    }
#undef GSTAGE
#pragma unroll
    for (int mi = 0; mi < 4; mi++)
#pragma unroll
        for (int ni = 0; ni < 4; ni++)
#pragma unroll
            for (int j = 0; j < 4; j++) {
                int r = m0 + wm * 64 + mi * 16 + lg * 4 + j;
                int c = n0 + wn * 64 + ni * 16 + lr;
                Cf[(long)r * Nn + c] = acc[mi][ni][j];
            }
}

extern "C" void kernel_launch(void* const* d_in, const int* in_sizes, int n_in,
                              void* d_out, int out_size, void* d_ws, size_t ws_size,
                              hipStream_t stream) {
    const float* hs    = (const float*)d_in[0];
    const float* wq    = (const float*)d_in[1];
    const float* wk    = (const float*)d_in[2];
    const float* wv    = (const float*)d_in[3];
    const float* wo    = (const float*)d_in[4];
    const float* qnw   = (const float*)d_in[5];
    const float* knw   = (const float*)d_in[6];
    const float* gwq   = (const float*)d_in[7];
    const float* gwk   = (const float*)d_in[8];
    const float* cosp  = (const float*)d_in[9];
    const float* sinp  = (const float*)d_in[10];
    const float* cosgq = (const float*)d_in[11];
    const float* singq = (const float*)d_in[12];
    const float* cosb  = (const float*)d_in[13];
    const float* sinb  = (const float*)d_in[14];
    // d_in[15] (block_attention_mask) is deterministic: n*64 <= s — never read.

    char* ws = (char*)d_ws;
    size_t off = 0;
    auto alloc = [&](size_t bytes) { void* p = ws + off; off += (bytes + 255) & ~255ULL; return p; };
    u16*  hsb    = (u16*)alloc((size_t)M_ * DM_ * 2);       // 8MB; dead after QKV gemm -> reused as attnb
    u16*  wqkvT  = (u16*)alloc(3072UL * 2048 * 2);          // 12MB combined [wqT; wkT; wvT]
    u16*  woT    = (u16*)alloc(2048UL * 2048 * 2);          // 8MB
    u16*  qkvb   = (u16*)alloc((size_t)M_ * 3072 * 2);      // 12MB bf16 QKV output
    u16*  qrb    = (u16*)alloc(2048UL * 2048 * 2);
    u16*  krb    = (u16*)alloc(2048UL * 512 * 2);
    u16*  knb    = (u16*)alloc(2048UL * 512 * 2);
    u16*  vtb    = (u16*)alloc(8UL * 128 * 1024 * 2);
    float* qgp   = (float*)alloc(2048UL * 4 * 128 * 4);
    float* kgp   = (float*)alloc(2UL * 16 * 4 * 128 * 4);
    float* gtraw = (float*)alloc(2UL * 16 * 1024 * 16 * 4);
    float* mfin  = (float*)alloc(2UL * 16 * 1024 * 4);
    float* lfin  = (float*)alloc(2UL * 16 * 1024 * 4);
    u16*  attnb  = hsb;                                     // alias: hsb dead before attn writes

    float* out = (float*)d_out;
    float* loss_slot = out + (size_t)M_ * DM_;

    // 1. convert hidden states + transpose all weights
    prep_kernel<<<11264, 256, 0, stream>>>(hs, wq, wk, wv, wo, hsb, wqkvT, woT);

    // 2. fused QKV projection: [2048][2048] @ [2048][3072] -> bf16 [2048][3072]
    gemm_bf16_kernel<<<dim3(24, 16), 256, 0, stream>>>(hsb, wqkvT, qkvb, 3072, 2048);

    // 3. RMS norm + RoPE + qgp  |  V transpose
    nrvt_kernel<<<3072, 256, 0, stream>>>(qkvb, qnw, knw, cosp, sinp, cosgq, singq, gwq,
                                          qrb, krb, knb, qgp, vtb);

    // 4. flash attention (512 balanced-dispatch blocks) | kp/kgp (128 blocks)
    attn_kp_kernel<<<640, 256, 0, stream>>>(qrb, krb, vtb, attnb, gtraw, mfin, lfin,
                                            knb, cosb, sinb, gwk, kgp, loss_slot);

    // 5. output projection -> f32 out | gate loss
    oproj_loss_kernel<<<512, 256, 0, stream>>>(attnb, woT, out,
                                               gtraw, mfin, lfin, qgp, kgp, loss_slot);
}